// Round 8
// baseline (909.705 us; speedup 1.0000x reference)
//
#include <hip/hip_runtime.h>
#include <math.h>

#define N_NODES 100000
#define N_EDGES 1600000
#define NB 64
#define F_IN 128
#define HDIM 64
#define NC 10
#define NBLK_NODES ((N_NODES + 255) / 256)

#define BSHIFT 9
#define BUCKET_NODES (1 << BSHIFT)                          // 512
#define NBUCK ((N_NODES + BUCKET_NODES - 1) >> BSHIFT)      // 196
#define EW_CHUNK 4096
#define EW_GRID ((N_EDGES + EW_CHUNK - 1) / EW_CHUNK)       // 391

// ---------- fused q/k/v/skip GEMM ----------
// 128x128 block tile (2 mats per pass, 2 passes). 8x8 thread tile in
// quad-split form (rows {tr*4, 64+tr*4}, cols {tc*4 matA, 64+tc*4 matB}).
// K-chunked LDS staging (32 k at a time): Xs+Wt = 33.8KB -> 4 blocks/CU.
// launch_bounds(256,4) caps VGPR at 128 for 4 waves/SIMD.
template<int K>
__global__ __launch_bounds__(256, 4) void qkvs_gemm_f(
    const float* __restrict__ xin,
    const float* __restrict__ Wq, const float* __restrict__ bq,
    const float* __restrict__ Wk, const float* __restrict__ bk,
    const float* __restrict__ Wv, const float* __restrict__ bv,
    const float* __restrict__ Ws, const float* __restrict__ bs,
    float* __restrict__ q, float* __restrict__ k,
    float* __restrict__ v, float* __restrict__ sk)
{
    __shared__ float Xs[32][132];   // transposed chunk: Xs[kk][row]
    __shared__ float Wt[32][132];   // transposed chunk: Wt[kk][col], 2 mats

    const int tid  = threadIdx.x;
    const int row0 = blockIdx.x * 128;
    const int tc   = tid & 15;      // col quad within 64
    const int tr   = tid >> 4;      // row quad within 64

    const int r    = tid & 127;     // staging row / col select
    const int kh   = (tid >> 7) * 16;   // 0 or 16 within chunk
    const int grow = row0 + r;
    const int wmat = r >> 6;        // 0/1 within pass
    const int wcol = r & 63;

    const float* Wm[4] = {Wq, Wk, Wv, Ws};
    const float* Bm[4] = {bq, bk, bv, bs};
    float*       Om[4] = {q, k, v, sk};

    #pragma unroll
    for (int pass = 0; pass < 2; pass++) {
        float acc[2][2][4][4] = {};           // [rowhalf][mathalf][i][j]

        for (int k0 = 0; k0 < K; k0 += 32) {
            __syncthreads();                  // protect LDS from previous reads
            {
                // stage X chunk: 128 rows x 32 k, transposed
                float tmp[16];
                if (grow < N_NODES) {
                    const float* p = xin + (size_t)grow * K + k0 + kh;
                    float4 a = *(const float4*)p;
                    float4 b = *(const float4*)(p + 4);
                    float4 c = *(const float4*)(p + 8);
                    float4 d = *(const float4*)(p + 12);
                    tmp[0]=a.x; tmp[1]=a.y; tmp[2]=a.z; tmp[3]=a.w;
                    tmp[4]=b.x; tmp[5]=b.y; tmp[6]=b.z; tmp[7]=b.w;
                    tmp[8]=c.x; tmp[9]=c.y; tmp[10]=c.z; tmp[11]=c.w;
                    tmp[12]=d.x; tmp[13]=d.y; tmp[14]=d.z; tmp[15]=d.w;
                } else {
                    #pragma unroll
                    for (int i = 0; i < 16; i++) tmp[i] = 0.f;
                }
                #pragma unroll
                for (int i = 0; i < 16; i++) Xs[kh + i][r] = tmp[i];

                // stage W chunk: 128 cols (2 mats) x 32 k, transposed
                const float* pw = Wm[pass * 2 + wmat] + (size_t)wcol * K + k0 + kh;
                float4 a = *(const float4*)pw;
                float4 b = *(const float4*)(pw + 4);
                float4 c = *(const float4*)(pw + 8);
                float4 d = *(const float4*)(pw + 12);
                float t16[16] = {a.x,a.y,a.z,a.w, b.x,b.y,b.z,b.w,
                                 c.x,c.y,c.z,c.w, d.x,d.y,d.z,d.w};
                #pragma unroll
                for (int i = 0; i < 16; i++) Wt[kh + i][r] = t16[i];
            }
            __syncthreads();

            #pragma unroll
            for (int kk = 0; kk < 32; kk++) {
                float4 x0 = *(const float4*)&Xs[kk][tr * 4];
                float4 x1 = *(const float4*)&Xs[kk][64 + tr * 4];
                float4 w0 = *(const float4*)&Wt[kk][tc * 4];
                float4 w1 = *(const float4*)&Wt[kk][64 + tc * 4];
                float xa[2][4] = {{x0.x, x0.y, x0.z, x0.w}, {x1.x, x1.y, x1.z, x1.w}};
                float wa[2][4] = {{w0.x, w0.y, w0.z, w0.w}, {w1.x, w1.y, w1.z, w1.w}};
                #pragma unroll
                for (int rh = 0; rh < 2; rh++)
                    #pragma unroll
                    for (int ch = 0; ch < 2; ch++)
                        #pragma unroll
                        for (int i = 0; i < 4; i++)
                            #pragma unroll
                            for (int j = 0; j < 4; j++)
                                acc[rh][ch][i][j] += xa[rh][i] * wa[ch][j];
            }
        }

        #pragma unroll
        for (int ch = 0; ch < 2; ch++) {
            int mat = pass * 2 + ch;
            float4 bias = *(const float4*)&Bm[mat][tc * 4];
            float ba[4] = {bias.x, bias.y, bias.z, bias.w};
            float* out = Om[mat];
            #pragma unroll
            for (int rh = 0; rh < 2; rh++) {
                #pragma unroll
                for (int i = 0; i < 4; i++) {
                    int gr = row0 + rh * 64 + tr * 4 + i;
                    if (gr < N_NODES) {
                        float4 rr;
                        rr.x = acc[rh][ch][i][0] + ba[0];
                        rr.y = acc[rh][ch][i][1] + ba[1];
                        rr.z = acc[rh][ch][i][2] + ba[2];
                        rr.w = acc[rh][ch][i][3] + ba[3];
                        *(float4*)&out[(size_t)gr * HDIM + tc * 4] = rr;
                    }
                }
            }
        }
    }
}

// ---------- CSR build, stage 1: per-dst degree + per-bucket counts ----------
__global__ __launch_bounds__(256) void count_deg_bucket(
    const int* __restrict__ ei, int* __restrict__ deg, int* __restrict__ bcnt)
{
    __shared__ int hist[NBUCK];
    for (int i = threadIdx.x; i < NBUCK; i += 256) hist[i] = 0;
    __syncthreads();
    int e0 = blockIdx.x * EW_CHUNK;
    #pragma unroll
    for (int i = 0; i < EW_CHUNK / 256; i++) {
        int e = e0 + i * 256 + threadIdx.x;
        if (e < N_EDGES) {
            int dst = ei[N_EDGES + e];
            atomicAdd(&deg[dst], 1);
            atomicAdd(&hist[dst >> BSHIFT], 1);
        }
    }
    __syncthreads();
    for (int i = threadIdx.x; i < NBUCK; i += 256)
        if (hist[i]) atomicAdd(&bcnt[i], hist[i]);
}

// ---------- row_ptr scan (3 kernels) ----------
__global__ __launch_bounds__(256) void deg_block_sum(
    const int* __restrict__ deg, int* __restrict__ bsum)
{
    __shared__ int sh[256];
    int i = blockIdx.x * 256 + threadIdx.x;
    sh[threadIdx.x] = (i < N_NODES) ? deg[i] : 0;
    __syncthreads();
    #pragma unroll
    for (int off = 128; off; off >>= 1) {
        if (threadIdx.x < off) sh[threadIdx.x] += sh[threadIdx.x + off];
        __syncthreads();
    }
    if (threadIdx.x == 0) bsum[blockIdx.x] = sh[0];
}

__global__ __launch_bounds__(512) void scan_bsum(int* __restrict__ bsum, int nb)
{
    __shared__ int sh[512];
    int t = threadIdx.x;
    int v = (t < nb) ? bsum[t] : 0;
    sh[t] = v;
    __syncthreads();
    for (int off = 1; off < 512; off <<= 1) {
        int u = (t >= off) ? sh[t - off] : 0;
        __syncthreads();
        sh[t] += u;
        __syncthreads();
    }
    if (t < nb) bsum[t] = sh[t] - v;   // exclusive
}

__global__ __launch_bounds__(256) void write_rowptr(
    const int* __restrict__ deg, const int* __restrict__ bsum,
    int* __restrict__ row_ptr)
{
    __shared__ int sh[256];
    int i = blockIdx.x * 256 + threadIdx.x;
    int v = (i < N_NODES) ? deg[i] : 0;
    sh[threadIdx.x] = v;
    __syncthreads();
    for (int off = 1; off < 256; off <<= 1) {
        int u = (threadIdx.x >= off) ? sh[threadIdx.x - off] : 0;
        __syncthreads();
        sh[threadIdx.x] += u;
        __syncthreads();
    }
    if (i < N_NODES) {
        int ex = bsum[blockIdx.x] + sh[threadIdx.x] - v;
        row_ptr[i] = ex;
        if (i == N_NODES - 1) row_ptr[N_NODES] = bsum[blockIdx.x] + sh[threadIdx.x];
    }
}

// ---------- CSR build, stage 2: bucket base scan ----------
__global__ __launch_bounds__(256) void scan_bucket(
    const int* __restrict__ bcnt, int* __restrict__ bbase, int* __restrict__ gcursor)
{
    __shared__ int sh[256];
    int t = threadIdx.x;
    int v = (t < NBUCK) ? bcnt[t] : 0;
    sh[t] = v;
    __syncthreads();
    for (int off = 1; off < 256; off <<= 1) {
        int u = (t >= off) ? sh[t - off] : 0;
        __syncthreads();
        sh[t] += u;
        __syncthreads();
    }
    if (t < NBUCK) { bbase[t] = sh[t] - v; gcursor[t] = sh[t] - v; }
}

// ---------- CSR build, stage 3: scatter edges into bucket-ordered array ----------
__global__ __launch_bounds__(256) void bucket_scatter(
    const int* __restrict__ ei, int* __restrict__ gcursor, int2* __restrict__ bedge)
{
    __shared__ int hist[NBUCK];
    __shared__ int base[NBUCK];
    for (int i = threadIdx.x; i < NBUCK; i += 256) hist[i] = 0;
    __syncthreads();
    int e0 = blockIdx.x * EW_CHUNK;
    #pragma unroll
    for (int i = 0; i < EW_CHUNK / 256; i++) {
        int e = e0 + i * 256 + threadIdx.x;
        if (e < N_EDGES) atomicAdd(&hist[ei[N_EDGES + e] >> BSHIFT], 1);
    }
    __syncthreads();
    for (int i = threadIdx.x; i < NBUCK; i += 256)
        base[i] = hist[i] ? atomicAdd(&gcursor[i], hist[i]) : 0;
    __syncthreads();
    for (int i = threadIdx.x; i < NBUCK; i += 256) hist[i] = 0;
    __syncthreads();
    #pragma unroll
    for (int i = 0; i < EW_CHUNK / 256; i++) {
        int e = e0 + i * 256 + threadIdx.x;
        if (e < N_EDGES) {
            int src = ei[e];
            int dst = ei[N_EDGES + e];
            int b = dst >> BSHIFT;
            int pos = base[b] + atomicAdd(&hist[b], 1);
            bedge[pos] = make_int2(src, dst);
        }
    }
}

// ---------- CSR build, stage 4: one WG per bucket, LDS cursors ----------
__global__ __launch_bounds__(256) void csr_from_buckets(
    const int2* __restrict__ bedge, const int* __restrict__ bbase,
    const int* __restrict__ bcnt, const int* __restrict__ row_ptr,
    int* __restrict__ csr_src)
{
    __shared__ int cur[BUCKET_NODES];
    int b = blockIdx.x;
    int dst0 = b << BSHIFT;
    for (int i = threadIdx.x; i < BUCKET_NODES; i += 256) {
        int d = dst0 + i;
        cur[i] = (d < N_NODES) ? row_ptr[d] : 0;
    }
    __syncthreads();
    int beg = bbase[b], cnt = bcnt[b];
    for (int i = threadIdx.x; i < cnt; i += 256) {
        int2 ed = bedge[beg + i];
        int pos = atomicAdd(&cur[ed.y - dst0], 1);
        csr_src[pos] = ed.x;
    }
}

// ---------- fused attention: wave per dst, 4 edges/iter, float4 features ----------
__global__ __launch_bounds__(256) void attn_fused(
    const int* __restrict__ row_ptr, const int* __restrict__ csr_src,
    const float* __restrict__ q, const float* __restrict__ k,
    const float* __restrict__ v, const float* __restrict__ skip,
    float* __restrict__ hout, int do_relu)
{
    int n = blockIdx.x * 4 + (threadIdx.x >> 6);
    if (n >= N_NODES) return;
    int lane = threadIdx.x & 63;
    int g = lane >> 4;
    int t = lane & 15;
    int beg = row_ptr[n], end = row_ptr[n + 1];

    float4 qf = *(const float4*)&q[(size_t)n * HDIM + t * 4];
    float m = -1e30f, s = 0.f;
    float4 acc = make_float4(0.f, 0.f, 0.f, 0.f);

    for (int i = beg; i < end; i += 4) {
        int e = i + g;
        bool valid = (e < end);
        int src = csr_src[valid ? e : beg];
        float4 kf = *(const float4*)&k[(size_t)src * HDIM + t * 4];
        float4 vf = *(const float4*)&v[(size_t)src * HDIM + t * 4];
        float p = qf.x * kf.x + qf.y * kf.y + qf.z * kf.z + qf.w * kf.w;
        p += __shfl_xor(p, 1, 64);
        p += __shfl_xor(p, 2, 64);
        p += __shfl_xor(p, 4, 64);
        p += __shfl_xor(p, 8, 64);
        float a = valid ? p * 0.125f : -INFINITY;
        float mn = fmaxf(m, a);
        float sc = __expf(m - mn);
        float ew = __expf(a - mn);
        s = s * sc + ew;
        acc.x = acc.x * sc + ew * vf.x;
        acc.y = acc.y * sc + ew * vf.y;
        acc.z = acc.z * sc + ew * vf.z;
        acc.w = acc.w * sc + ew * vf.w;
        m = mn;
    }

    #pragma unroll
    for (int off = 16; off <= 32; off <<= 1) {
        float m2 = __shfl_xor(m, off, 64);
        float s2 = __shfl_xor(s, off, 64);
        float ax = __shfl_xor(acc.x, off, 64);
        float ay = __shfl_xor(acc.y, off, 64);
        float az = __shfl_xor(acc.z, off, 64);
        float aw = __shfl_xor(acc.w, off, 64);
        float mn = fmaxf(m, m2);
        float c1 = __expf(m - mn);
        float c2 = __expf(m2 - mn);
        s = s * c1 + s2 * c2;
        acc.x = acc.x * c1 + ax * c2;
        acc.y = acc.y * c1 + ay * c2;
        acc.z = acc.z * c1 + az * c2;
        acc.w = acc.w * c1 + aw * c2;
        m = mn;
    }

    if (g == 0) {
        float inv = (s > 0.f) ? (1.f / s) : 0.f;
        float4 sk4 = *(const float4*)&skip[(size_t)n * HDIM + t * 4];
        float4 val;
        val.x = acc.x * inv + sk4.x;
        val.y = acc.y * inv + sk4.y;
        val.z = acc.z * inv + sk4.z;
        val.w = acc.w * inv + sk4.w;
        if (do_relu) {
            val.x = fmaxf(val.x, 0.f);
            val.y = fmaxf(val.y, 0.f);
            val.z = fmaxf(val.z, 0.f);
            val.w = fmaxf(val.w, 0.f);
        }
        *(float4*)&hout[(size_t)n * HDIM + t * 4] = val;
    }
}

// ---------- mean pool: run-length accumulate (batch sorted) ----------
__global__ __launch_bounds__(256) void pool_kernel(
    const float* __restrict__ h, const int* __restrict__ batch,
    float* __restrict__ sums, float* __restrict__ cnt)
{
    int wid = blockIdx.x * 4 + (threadIdx.x >> 6);
    int n0 = wid * 64;
    if (n0 >= N_NODES) return;
    int lane = threadIdx.x & 63;
    int nend = min(n0 + 64, N_NODES);
    float acc = 0.f;
    int b_cur = batch[n0];
    int run = 0;
    for (int n = n0; n < nend; n++) {
        int b = batch[n];
        if (b != b_cur) {
            atomicAdd(&sums[b_cur * HDIM + lane], acc);
            if (lane == 0) atomicAdd(&cnt[b_cur], (float)run);
            acc = 0.f; run = 0; b_cur = b;
        }
        acc += h[(size_t)n * HDIM + lane];
        run++;
    }
    atomicAdd(&sums[b_cur * HDIM + lane], acc);
    if (lane == 0) atomicAdd(&cnt[b_cur], (float)run);
}

// ---------- head ----------
__global__ void head_kernel(
    const float* __restrict__ sums, const float* __restrict__ cnt,
    const float* __restrict__ Wl, const float* __restrict__ bl,
    float* __restrict__ out)
{
    int tid = threadIdx.x;
    if (tid >= NB * NC) return;
    int b = tid / NC, c = tid % NC;
    float cc = fmaxf(cnt[b], 1.0f);
    float acc = bl[c];
    #pragma unroll
    for (int f = 0; f < HDIM; f++)
        acc += (sums[b * HDIM + f] / cc) * Wl[c * HDIM + f];
    out[tid] = acc;
}

extern "C" void kernel_launch(void* const* d_in, const int* in_sizes, int n_in,
                              void* d_out, int out_size, void* d_ws, size_t ws_size,
                              hipStream_t stream)
{
    const float* x     = (const float*)d_in[0];
    const int*   ei    = (const int*)d_in[1];
    const int*   batch = (const int*)d_in[2];

    const float* W[3][4];
    const float* B[3][4];
    for (int l = 0; l < 3; l++)
        for (int j = 0; j < 4; j++) {
            W[l][j] = (const float*)d_in[3 + l * 8 + j * 2];
            B[l][j] = (const float*)d_in[3 + l * 8 + j * 2 + 1];
        }
    const float* Wl = (const float*)d_in[27];
    const float* bl = (const float*)d_in[28];
    float* out = (float*)d_out;

    const size_t NF = (size_t)N_NODES * HDIM;
    char* w = (char*)d_ws;
    float* h       = (float*)w;  w += NF * 4;
    float* q       = (float*)w;  w += NF * 4;
    float* kbuf    = (float*)w;  w += NF * 4;
    float* v       = (float*)w;  w += NF * 4;
    float* skip    = (float*)w;  w += NF * 4;
    int*   csr_src = (int*)w;    w += (size_t)N_EDGES * 4;
    int2*  bedge   = (int2*)w;   w += (size_t)N_EDGES * 8;
    int*   row_ptr = (int*)w;    w += (size_t)(N_NODES + 1) * 4;
    int*   deg     = (int*)w;    w += (size_t)N_NODES * 4;
    int*   bcnt    = (int*)w;    w += (size_t)NBUCK * 4;     // adjacent to deg: one memset
    int*   bbase   = (int*)w;    w += (size_t)NBUCK * 4;
    int*   gcursor = (int*)w;    w += (size_t)NBUCK * 4;
    int*   bsum    = (int*)w;    w += (size_t)NBLK_NODES * 4;
    float* sums    = (float*)w;  w += (size_t)NB * HDIM * 4;
    float* cnt     = (float*)w;  w += (size_t)NB * 4;

    const int gemm_gx = (N_NODES + 127) / 128;
    const int node_gx = (N_NODES + 3) / 4;
    const int pool_gx = (N_NODES + 64 * 4 - 1) / (64 * 4);

    // ----- CSR build via LDS-staged counting sort (once; shared by all layers) -----
    hipMemsetAsync(deg, 0, (size_t)(N_NODES + NBUCK) * 4, stream);   // deg + bcnt
    count_deg_bucket<<<EW_GRID, 256, 0, stream>>>(ei, deg, bcnt);
    deg_block_sum<<<NBLK_NODES, 256, 0, stream>>>(deg, bsum);
    scan_bsum<<<1, 512, 0, stream>>>(bsum, NBLK_NODES);
    write_rowptr<<<NBLK_NODES, 256, 0, stream>>>(deg, bsum, row_ptr);
    scan_bucket<<<1, 256, 0, stream>>>(bcnt, bbase, gcursor);
    bucket_scatter<<<EW_GRID, 256, 0, stream>>>(ei, gcursor, bedge);
    csr_from_buckets<<<NBUCK, 256, 0, stream>>>(bedge, bbase, bcnt, row_ptr, csr_src);

    for (int l = 0; l < 3; l++) {
        if (l == 0) {
            qkvs_gemm_f<F_IN><<<gemm_gx, 256, 0, stream>>>(
                x, W[0][0], B[0][0], W[0][1], B[0][1],
                   W[0][2], B[0][2], W[0][3], B[0][3], q, kbuf, v, skip);
        } else {
            qkvs_gemm_f<HDIM><<<gemm_gx, 256, 0, stream>>>(
                h, W[l][0], B[l][0], W[l][1], B[l][1],
                   W[l][2], B[l][2], W[l][3], B[l][3], q, kbuf, v, skip);
        }
        attn_fused<<<node_gx, 256, 0, stream>>>(
            row_ptr, csr_src, q, kbuf, v, skip, h, l < 2 ? 1 : 0);
    }

    hipMemsetAsync(sums, 0, (size_t)NB * HDIM * 4, stream);
    hipMemsetAsync(cnt,  0, (size_t)NB * 4, stream);
    pool_kernel<<<pool_gx, 256, 0, stream>>>(h, batch, sums, cnt);
    head_kernel<<<1, 640, 0, stream>>>(sums, cnt, Wl, bl, out);
}

// Round 9
// 867.193 us; speedup vs baseline: 1.0490x; 1.0490x over previous
//
#include <hip/hip_runtime.h>
#include <math.h>

#define N_NODES 100000
#define N_EDGES 1600000
#define NB 64
#define F_IN 128
#define HDIM 64
#define NC 10
#define NBLK_NODES ((N_NODES + 255) / 256)

#define BSHIFT 9
#define BUCKET_NODES (1 << BSHIFT)                          // 512
#define NBUCK ((N_NODES + BUCKET_NODES - 1) >> BSHIFT)      // 196
#define EW_CHUNK 4096
#define EW_GRID ((N_EDGES + EW_CHUNK - 1) / EW_CHUNK)       // 391

// ---------- fused q/k/v/skip GEMM ----------
// 128x128 block tile (2 mats per pass, 2 passes). 8x8 thread tile in
// quad-split form (rows {tr*4, 64+tr*4}, cols {tc*4 matA, 64+tc*4 matB}).
// K-chunked LDS staging (32 k at a time): Xs+Wt = 33.8KB -> LDS allows 4 blk/CU.
// NO min-waves clause: r8's (256,4) capped VGPR at 128 -> acc spilled to
// scratch (600 MB HBM/dispatch). Let the allocator take ~132 VGPR, 3 blk/CU.
template<int K>
__global__ __launch_bounds__(256) void qkvs_gemm_f(
    const float* __restrict__ xin,
    const float* __restrict__ Wq, const float* __restrict__ bq,
    const float* __restrict__ Wk, const float* __restrict__ bk,
    const float* __restrict__ Wv, const float* __restrict__ bv,
    const float* __restrict__ Ws, const float* __restrict__ bs,
    float* __restrict__ q, float* __restrict__ k,
    float* __restrict__ v, float* __restrict__ sk)
{
    __shared__ float Xs[32][132];   // transposed chunk: Xs[kk][row]
    __shared__ float Wt[32][132];   // transposed chunk: Wt[kk][col], 2 mats

    const int tid  = threadIdx.x;
    const int row0 = blockIdx.x * 128;
    const int tc   = tid & 15;      // col quad within 64
    const int tr   = tid >> 4;      // row quad within 64

    const int r    = tid & 127;     // staging row / col select
    const int kh   = (tid >> 7) * 16;   // 0 or 16 within chunk
    const int grow = row0 + r;
    const int wmat = r >> 6;        // 0/1 within pass
    const int wcol = r & 63;

    const float* Wm[4] = {Wq, Wk, Wv, Ws};
    const float* Bm[4] = {bq, bk, bv, bs};
    float*       Om[4] = {q, k, v, sk};

    #pragma unroll
    for (int pass = 0; pass < 2; pass++) {
        float acc[2][2][4][4] = {};           // [rowhalf][mathalf][i][j]

        for (int k0 = 0; k0 < K; k0 += 32) {
            __syncthreads();                  // protect LDS from previous reads
            {
                // stage X chunk: 128 rows x 32 k, transposed
                float tmp[16];
                if (grow < N_NODES) {
                    const float* p = xin + (size_t)grow * K + k0 + kh;
                    float4 a = *(const float4*)p;
                    float4 b = *(const float4*)(p + 4);
                    float4 c = *(const float4*)(p + 8);
                    float4 d = *(const float4*)(p + 12);
                    tmp[0]=a.x; tmp[1]=a.y; tmp[2]=a.z; tmp[3]=a.w;
                    tmp[4]=b.x; tmp[5]=b.y; tmp[6]=b.z; tmp[7]=b.w;
                    tmp[8]=c.x; tmp[9]=c.y; tmp[10]=c.z; tmp[11]=c.w;
                    tmp[12]=d.x; tmp[13]=d.y; tmp[14]=d.z; tmp[15]=d.w;
                } else {
                    #pragma unroll
                    for (int i = 0; i < 16; i++) tmp[i] = 0.f;
                }
                #pragma unroll
                for (int i = 0; i < 16; i++) Xs[kh + i][r] = tmp[i];

                // stage W chunk: 128 cols (2 mats) x 32 k, transposed
                const float* pw = Wm[pass * 2 + wmat] + (size_t)wcol * K + k0 + kh;
                float4 a = *(const float4*)pw;
                float4 b = *(const float4*)(pw + 4);
                float4 c = *(const float4*)(pw + 8);
                float4 d = *(const float4*)(pw + 12);
                float t16[16] = {a.x,a.y,a.z,a.w, b.x,b.y,b.z,b.w,
                                 c.x,c.y,c.z,c.w, d.x,d.y,d.z,d.w};
                #pragma unroll
                for (int i = 0; i < 16; i++) Wt[kh + i][r] = t16[i];
            }
            __syncthreads();

            #pragma unroll
            for (int kk = 0; kk < 32; kk++) {
                float4 x0 = *(const float4*)&Xs[kk][tr * 4];
                float4 x1 = *(const float4*)&Xs[kk][64 + tr * 4];
                float4 w0 = *(const float4*)&Wt[kk][tc * 4];
                float4 w1 = *(const float4*)&Wt[kk][64 + tc * 4];
                float xa[2][4] = {{x0.x, x0.y, x0.z, x0.w}, {x1.x, x1.y, x1.z, x1.w}};
                float wa[2][4] = {{w0.x, w0.y, w0.z, w0.w}, {w1.x, w1.y, w1.z, w1.w}};
                #pragma unroll
                for (int rh = 0; rh < 2; rh++)
                    #pragma unroll
                    for (int ch = 0; ch < 2; ch++)
                        #pragma unroll
                        for (int i = 0; i < 4; i++)
                            #pragma unroll
                            for (int j = 0; j < 4; j++)
                                acc[rh][ch][i][j] += xa[rh][i] * wa[ch][j];
            }
        }

        #pragma unroll
        for (int ch = 0; ch < 2; ch++) {
            int mat = pass * 2 + ch;
            float4 bias = *(const float4*)&Bm[mat][tc * 4];
            float ba[4] = {bias.x, bias.y, bias.z, bias.w};
            float* out = Om[mat];
            #pragma unroll
            for (int rh = 0; rh < 2; rh++) {
                #pragma unroll
                for (int i = 0; i < 4; i++) {
                    int gr = row0 + rh * 64 + tr * 4 + i;
                    if (gr < N_NODES) {
                        float4 rr;
                        rr.x = acc[rh][ch][i][0] + ba[0];
                        rr.y = acc[rh][ch][i][1] + ba[1];
                        rr.z = acc[rh][ch][i][2] + ba[2];
                        rr.w = acc[rh][ch][i][3] + ba[3];
                        *(float4*)&out[(size_t)gr * HDIM + tc * 4] = rr;
                    }
                }
            }
        }
    }
}

// ---------- CSR build, stage 1: per-dst degree + per-bucket counts ----------
__global__ __launch_bounds__(256) void count_deg_bucket(
    const int* __restrict__ ei, int* __restrict__ deg, int* __restrict__ bcnt)
{
    __shared__ int hist[NBUCK];
    for (int i = threadIdx.x; i < NBUCK; i += 256) hist[i] = 0;
    __syncthreads();
    int e0 = blockIdx.x * EW_CHUNK;
    #pragma unroll
    for (int i = 0; i < EW_CHUNK / 256; i++) {
        int e = e0 + i * 256 + threadIdx.x;
        if (e < N_EDGES) {
            int dst = ei[N_EDGES + e];
            atomicAdd(&deg[dst], 1);
            atomicAdd(&hist[dst >> BSHIFT], 1);
        }
    }
    __syncthreads();
    for (int i = threadIdx.x; i < NBUCK; i += 256)
        if (hist[i]) atomicAdd(&bcnt[i], hist[i]);
}

// ---------- row_ptr scan (3 kernels) ----------
__global__ __launch_bounds__(256) void deg_block_sum(
    const int* __restrict__ deg, int* __restrict__ bsum)
{
    __shared__ int sh[256];
    int i = blockIdx.x * 256 + threadIdx.x;
    sh[threadIdx.x] = (i < N_NODES) ? deg[i] : 0;
    __syncthreads();
    #pragma unroll
    for (int off = 128; off; off >>= 1) {
        if (threadIdx.x < off) sh[threadIdx.x] += sh[threadIdx.x + off];
        __syncthreads();
    }
    if (threadIdx.x == 0) bsum[blockIdx.x] = sh[0];
}

__global__ __launch_bounds__(512) void scan_bsum(int* __restrict__ bsum, int nb)
{
    __shared__ int sh[512];
    int t = threadIdx.x;
    int v = (t < nb) ? bsum[t] : 0;
    sh[t] = v;
    __syncthreads();
    for (int off = 1; off < 512; off <<= 1) {
        int u = (t >= off) ? sh[t - off] : 0;
        __syncthreads();
        sh[t] += u;
        __syncthreads();
    }
    if (t < nb) bsum[t] = sh[t] - v;   // exclusive
}

__global__ __launch_bounds__(256) void write_rowptr(
    const int* __restrict__ deg, const int* __restrict__ bsum,
    int* __restrict__ row_ptr)
{
    __shared__ int sh[256];
    int i = blockIdx.x * 256 + threadIdx.x;
    int v = (i < N_NODES) ? deg[i] : 0;
    sh[threadIdx.x] = v;
    __syncthreads();
    for (int off = 1; off < 256; off <<= 1) {
        int u = (threadIdx.x >= off) ? sh[threadIdx.x - off] : 0;
        __syncthreads();
        sh[threadIdx.x] += u;
        __syncthreads();
    }
    if (i < N_NODES) {
        int ex = bsum[blockIdx.x] + sh[threadIdx.x] - v;
        row_ptr[i] = ex;
        if (i == N_NODES - 1) row_ptr[N_NODES] = bsum[blockIdx.x] + sh[threadIdx.x];
    }
}

// ---------- CSR build, stage 2: bucket base scan ----------
__global__ __launch_bounds__(256) void scan_bucket(
    const int* __restrict__ bcnt, int* __restrict__ bbase, int* __restrict__ gcursor)
{
    __shared__ int sh[256];
    int t = threadIdx.x;
    int v = (t < NBUCK) ? bcnt[t] : 0;
    sh[t] = v;
    __syncthreads();
    for (int off = 1; off < 256; off <<= 1) {
        int u = (t >= off) ? sh[t - off] : 0;
        __syncthreads();
        sh[t] += u;
        __syncthreads();
    }
    if (t < NBUCK) { bbase[t] = sh[t] - v; gcursor[t] = sh[t] - v; }
}

// ---------- CSR build, stage 3: scatter edges into bucket-ordered array ----------
__global__ __launch_bounds__(256) void bucket_scatter(
    const int* __restrict__ ei, int* __restrict__ gcursor, int2* __restrict__ bedge)
{
    __shared__ int hist[NBUCK];
    __shared__ int base[NBUCK];
    for (int i = threadIdx.x; i < NBUCK; i += 256) hist[i] = 0;
    __syncthreads();
    int e0 = blockIdx.x * EW_CHUNK;
    #pragma unroll
    for (int i = 0; i < EW_CHUNK / 256; i++) {
        int e = e0 + i * 256 + threadIdx.x;
        if (e < N_EDGES) atomicAdd(&hist[ei[N_EDGES + e] >> BSHIFT], 1);
    }
    __syncthreads();
    for (int i = threadIdx.x; i < NBUCK; i += 256)
        base[i] = hist[i] ? atomicAdd(&gcursor[i], hist[i]) : 0;
    __syncthreads();
    for (int i = threadIdx.x; i < NBUCK; i += 256) hist[i] = 0;
    __syncthreads();
    #pragma unroll
    for (int i = 0; i < EW_CHUNK / 256; i++) {
        int e = e0 + i * 256 + threadIdx.x;
        if (e < N_EDGES) {
            int src = ei[e];
            int dst = ei[N_EDGES + e];
            int b = dst >> BSHIFT;
            int pos = base[b] + atomicAdd(&hist[b], 1);
            bedge[pos] = make_int2(src, dst);
        }
    }
}

// ---------- CSR build, stage 4: one WG per bucket, LDS cursors ----------
__global__ __launch_bounds__(256) void csr_from_buckets(
    const int2* __restrict__ bedge, const int* __restrict__ bbase,
    const int* __restrict__ bcnt, const int* __restrict__ row_ptr,
    int* __restrict__ csr_src)
{
    __shared__ int cur[BUCKET_NODES];
    int b = blockIdx.x;
    int dst0 = b << BSHIFT;
    for (int i = threadIdx.x; i < BUCKET_NODES; i += 256) {
        int d = dst0 + i;
        cur[i] = (d < N_NODES) ? row_ptr[d] : 0;
    }
    __syncthreads();
    int beg = bbase[b], cnt = bcnt[b];
    for (int i = threadIdx.x; i < cnt; i += 256) {
        int2 ed = bedge[beg + i];
        int pos = atomicAdd(&cur[ed.y - dst0], 1);
        csr_src[pos] = ed.x;
    }
}

// ---------- fused attention: wave per dst, 4 edges/iter, float4 features ----------
__global__ __launch_bounds__(256) void attn_fused(
    const int* __restrict__ row_ptr, const int* __restrict__ csr_src,
    const float* __restrict__ q, const float* __restrict__ k,
    const float* __restrict__ v, const float* __restrict__ skip,
    float* __restrict__ hout, int do_relu)
{
    int n = blockIdx.x * 4 + (threadIdx.x >> 6);
    if (n >= N_NODES) return;
    int lane = threadIdx.x & 63;
    int g = lane >> 4;
    int t = lane & 15;
    int beg = row_ptr[n], end = row_ptr[n + 1];

    float4 qf = *(const float4*)&q[(size_t)n * HDIM + t * 4];
    float m = -1e30f, s = 0.f;
    float4 acc = make_float4(0.f, 0.f, 0.f, 0.f);

    for (int i = beg; i < end; i += 4) {
        int e = i + g;
        bool valid = (e < end);
        int src = csr_src[valid ? e : beg];
        float4 kf = *(const float4*)&k[(size_t)src * HDIM + t * 4];
        float4 vf = *(const float4*)&v[(size_t)src * HDIM + t * 4];
        float p = qf.x * kf.x + qf.y * kf.y + qf.z * kf.z + qf.w * kf.w;
        p += __shfl_xor(p, 1, 64);
        p += __shfl_xor(p, 2, 64);
        p += __shfl_xor(p, 4, 64);
        p += __shfl_xor(p, 8, 64);
        float a = valid ? p * 0.125f : -INFINITY;
        float mn = fmaxf(m, a);
        float sc = __expf(m - mn);
        float ew = __expf(a - mn);
        s = s * sc + ew;
        acc.x = acc.x * sc + ew * vf.x;
        acc.y = acc.y * sc + ew * vf.y;
        acc.z = acc.z * sc + ew * vf.z;
        acc.w = acc.w * sc + ew * vf.w;
        m = mn;
    }

    #pragma unroll
    for (int off = 16; off <= 32; off <<= 1) {
        float m2 = __shfl_xor(m, off, 64);
        float s2 = __shfl_xor(s, off, 64);
        float ax = __shfl_xor(acc.x, off, 64);
        float ay = __shfl_xor(acc.y, off, 64);
        float az = __shfl_xor(acc.z, off, 64);
        float aw = __shfl_xor(acc.w, off, 64);
        float mn = fmaxf(m, m2);
        float c1 = __expf(m - mn);
        float c2 = __expf(m2 - mn);
        s = s * c1 + s2 * c2;
        acc.x = acc.x * c1 + ax * c2;
        acc.y = acc.y * c1 + ay * c2;
        acc.z = acc.z * c1 + az * c2;
        acc.w = acc.w * c1 + aw * c2;
        m = mn;
    }

    if (g == 0) {
        float inv = (s > 0.f) ? (1.f / s) : 0.f;
        float4 sk4 = *(const float4*)&skip[(size_t)n * HDIM + t * 4];
        float4 val;
        val.x = acc.x * inv + sk4.x;
        val.y = acc.y * inv + sk4.y;
        val.z = acc.z * inv + sk4.z;
        val.w = acc.w * inv + sk4.w;
        if (do_relu) {
            val.x = fmaxf(val.x, 0.f);
            val.y = fmaxf(val.y, 0.f);
            val.z = fmaxf(val.z, 0.f);
            val.w = fmaxf(val.w, 0.f);
        }
        *(float4*)&hout[(size_t)n * HDIM + t * 4] = val;
    }
}

// ---------- mean pool: run-length accumulate (batch sorted) ----------
__global__ __launch_bounds__(256) void pool_kernel(
    const float* __restrict__ h, const int* __restrict__ batch,
    float* __restrict__ sums, float* __restrict__ cnt)
{
    int wid = blockIdx.x * 4 + (threadIdx.x >> 6);
    int n0 = wid * 64;
    if (n0 >= N_NODES) return;
    int lane = threadIdx.x & 63;
    int nend = min(n0 + 64, N_NODES);
    float acc = 0.f;
    int b_cur = batch[n0];
    int run = 0;
    for (int n = n0; n < nend; n++) {
        int b = batch[n];
        if (b != b_cur) {
            atomicAdd(&sums[b_cur * HDIM + lane], acc);
            if (lane == 0) atomicAdd(&cnt[b_cur], (float)run);
            acc = 0.f; run = 0; b_cur = b;
        }
        acc += h[(size_t)n * HDIM + lane];
        run++;
    }
    atomicAdd(&sums[b_cur * HDIM + lane], acc);
    if (lane == 0) atomicAdd(&cnt[b_cur], (float)run);
}

// ---------- head ----------
__global__ void head_kernel(
    const float* __restrict__ sums, const float* __restrict__ cnt,
    const float* __restrict__ Wl, const float* __restrict__ bl,
    float* __restrict__ out)
{
    int tid = threadIdx.x;
    if (tid >= NB * NC) return;
    int b = tid / NC, c = tid % NC;
    float cc = fmaxf(cnt[b], 1.0f);
    float acc = bl[c];
    #pragma unroll
    for (int f = 0; f < HDIM; f++)
        acc += (sums[b * HDIM + f] / cc) * Wl[c * HDIM + f];
    out[tid] = acc;
}

extern "C" void kernel_launch(void* const* d_in, const int* in_sizes, int n_in,
                              void* d_out, int out_size, void* d_ws, size_t ws_size,
                              hipStream_t stream)
{
    const float* x     = (const float*)d_in[0];
    const int*   ei    = (const int*)d_in[1];
    const int*   batch = (const int*)d_in[2];

    const float* W[3][4];
    const float* B[3][4];
    for (int l = 0; l < 3; l++)
        for (int j = 0; j < 4; j++) {
            W[l][j] = (const float*)d_in[3 + l * 8 + j * 2];
            B[l][j] = (const float*)d_in[3 + l * 8 + j * 2 + 1];
        }
    const float* Wl = (const float*)d_in[27];
    const float* bl = (const float*)d_in[28];
    float* out = (float*)d_out;

    const size_t NF = (size_t)N_NODES * HDIM;
    char* w = (char*)d_ws;
    float* h       = (float*)w;  w += NF * 4;
    float* q       = (float*)w;  w += NF * 4;
    float* kbuf    = (float*)w;  w += NF * 4;
    float* v       = (float*)w;  w += NF * 4;
    float* skip    = (float*)w;  w += NF * 4;
    int*   csr_src = (int*)w;    w += (size_t)N_EDGES * 4;
    int2*  bedge   = (int2*)w;   w += (size_t)N_EDGES * 8;
    int*   row_ptr = (int*)w;    w += (size_t)(N_NODES + 1) * 4;
    int*   deg     = (int*)w;    w += (size_t)N_NODES * 4;
    int*   bcnt    = (int*)w;    w += (size_t)NBUCK * 4;     // adjacent to deg: one memset
    int*   bbase   = (int*)w;    w += (size_t)NBUCK * 4;
    int*   gcursor = (int*)w;    w += (size_t)NBUCK * 4;
    int*   bsum    = (int*)w;    w += (size_t)NBLK_NODES * 4;
    float* sums    = (float*)w;  w += (size_t)NB * HDIM * 4;
    float* cnt     = (float*)w;  w += (size_t)NB * 4;

    const int gemm_gx = (N_NODES + 127) / 128;
    const int node_gx = (N_NODES + 3) / 4;
    const int pool_gx = (N_NODES + 64 * 4 - 1) / (64 * 4);

    // ----- CSR build via LDS-staged counting sort (once; shared by all layers) -----
    hipMemsetAsync(deg, 0, (size_t)(N_NODES + NBUCK) * 4, stream);   // deg + bcnt
    count_deg_bucket<<<EW_GRID, 256, 0, stream>>>(ei, deg, bcnt);
    deg_block_sum<<<NBLK_NODES, 256, 0, stream>>>(deg, bsum);
    scan_bsum<<<1, 512, 0, stream>>>(bsum, NBLK_NODES);
    write_rowptr<<<NBLK_NODES, 256, 0, stream>>>(deg, bsum, row_ptr);
    scan_bucket<<<1, 256, 0, stream>>>(bcnt, bbase, gcursor);
    bucket_scatter<<<EW_GRID, 256, 0, stream>>>(ei, gcursor, bedge);
    csr_from_buckets<<<NBUCK, 256, 0, stream>>>(bedge, bbase, bcnt, row_ptr, csr_src);

    for (int l = 0; l < 3; l++) {
        if (l == 0) {
            qkvs_gemm_f<F_IN><<<gemm_gx, 256, 0, stream>>>(
                x, W[0][0], B[0][0], W[0][1], B[0][1],
                   W[0][2], B[0][2], W[0][3], B[0][3], q, kbuf, v, skip);
        } else {
            qkvs_gemm_f<HDIM><<<gemm_gx, 256, 0, stream>>>(
                h, W[l][0], B[l][0], W[l][1], B[l][1],
                   W[l][2], B[l][2], W[l][3], B[l][3], q, kbuf, v, skip);
        }
        attn_fused<<<node_gx, 256, 0, stream>>>(
            row_ptr, csr_src, q, kbuf, v, skip, h, l < 2 ? 1 : 0);
    }

    hipMemsetAsync(sums, 0, (size_t)NB * HDIM * 4, stream);
    hipMemsetAsync(cnt,  0, (size_t)NB * 4, stream);
    pool_kernel<<<pool_gx, 256, 0, stream>>>(h, batch, sums, cnt);
    head_kernel<<<1, 640, 0, stream>>>(sums, cnt, Wl, bl, out);
}

// Round 10
// 690.001 us; speedup vs baseline: 1.3184x; 1.2568x over previous
//
#include <hip/hip_runtime.h>
#include <math.h>

#define N_NODES 100000
#define N_EDGES 1600000
#define NB 64
#define F_IN 128
#define HDIM 64
#define NC 10

#define BSHIFT 9
#define BUCKET_NODES (1 << BSHIFT)                          // 512
#define NBUCK ((N_NODES + BUCKET_NODES - 1) >> BSHIFT)      // 196
#define EW_CHUNK 4096
#define EW_GRID ((N_EDGES + EW_CHUNK - 1) / EW_CHUNK)       // 391

// ---------- fused q/k/v/skip GEMM (r6 structure: X staged once, full-W per mat) ----------
// 64-row tile, 4x4 thread tile, grid = ceil(N/64). Known-good: 130us l0.
template<int K>
__global__ __launch_bounds__(256) void qkvs_gemm_f(
    const float* __restrict__ xin,
    const float* __restrict__ Wq, const float* __restrict__ bq,
    const float* __restrict__ Wk, const float* __restrict__ bk,
    const float* __restrict__ Wv, const float* __restrict__ bv,
    const float* __restrict__ Ws, const float* __restrict__ bs,
    float* __restrict__ q, float* __restrict__ k,
    float* __restrict__ v, float* __restrict__ sk)
{
    __shared__ float Xs[K][68];    // transposed: Xs[k][row]
    __shared__ float Wt[K][68];    // transposed: Wt[k][col], full K for one mat

    const int row0 = blockIdx.x * 64;
    const int tid  = threadIdx.x;
    const int tc   = tid & 15;     // col group (4 cols each)
    const int tr   = tid >> 4;     // row group (4 rows each)
    const int lrow = tid >> 2;     // 0..63
    const int lk   = (tid & 3) * 8;

    // stage full X tile (64 rows x K) transposed
    for (int k0 = 0; k0 < K; k0 += 32) {
        int grow = row0 + lrow;
        float tmp[8];
        if (grow < N_NODES) {
            const float* p = xin + (size_t)grow * K + k0 + lk;
            float4 a = *(const float4*)p;
            float4 c = *(const float4*)(p + 4);
            tmp[0]=a.x; tmp[1]=a.y; tmp[2]=a.z; tmp[3]=a.w;
            tmp[4]=c.x; tmp[5]=c.y; tmp[6]=c.z; tmp[7]=c.w;
        } else {
            #pragma unroll
            for (int i = 0; i < 8; i++) tmp[i] = 0.f;
        }
        #pragma unroll
        for (int i = 0; i < 8; i++) Xs[k0 + lk + i][lrow] = tmp[i];
    }

    const float* Wm[4] = {Wq, Wk, Wv, Ws};
    const float* Bm[4] = {bq, bk, bv, bs};
    float*       Om[4] = {q, k, v, sk};

    for (int mat = 0; mat < 4; mat++) {
        if (mat) __syncthreads();          // protect Wt from previous compute
        // stage full W (64 out-cols x K) transposed
        for (int k0 = 0; k0 < K; k0 += 32) {
            const float* pw = Wm[mat] + (size_t)lrow * K + k0 + lk;
            float4 a = *(const float4*)pw;
            float4 c = *(const float4*)(pw + 4);
            float wt[8] = {a.x, a.y, a.z, a.w, c.x, c.y, c.z, c.w};
            #pragma unroll
            for (int i = 0; i < 8; i++) Wt[k0 + lk + i][lrow] = wt[i];
        }
        __syncthreads();                   // covers Xs (first mat) + Wt

        float acc[4][4] = {};
        #pragma unroll 8
        for (int kk = 0; kk < K; kk++) {
            float4 xf = *(const float4*)&Xs[kk][tr * 4];
            float4 wf = *(const float4*)&Wt[kk][tc * 4];
            float xa[4] = {xf.x, xf.y, xf.z, xf.w};
            float wa[4] = {wf.x, wf.y, wf.z, wf.w};
            #pragma unroll
            for (int i = 0; i < 4; i++)
                #pragma unroll
                for (int j = 0; j < 4; j++)
                    acc[i][j] += xa[i] * wa[j];
        }

        float4 bias = *(const float4*)&Bm[mat][tc * 4];
        float ba[4] = {bias.x, bias.y, bias.z, bias.w};
        float* out = Om[mat];
        #pragma unroll
        for (int i = 0; i < 4; i++) {
            int grow = row0 + tr * 4 + i;
            if (grow < N_NODES) {
                float4 r;
                r.x = acc[i][0] + ba[0];
                r.y = acc[i][1] + ba[1];
                r.z = acc[i][2] + ba[2];
                r.w = acc[i][3] + ba[3];
                *(float4*)&out[(size_t)grow * HDIM + tc * 4] = r;
            }
        }
    }
}

// ---------- CSR build, stage 1: per-bucket edge counts (LDS hist only) ----------
__global__ __launch_bounds__(256) void count_bucket(
    const int* __restrict__ ei, int* __restrict__ bcnt)
{
    __shared__ int hist[NBUCK];
    for (int i = threadIdx.x; i < NBUCK; i += 256) hist[i] = 0;
    __syncthreads();
    int e0 = blockIdx.x * EW_CHUNK;
    #pragma unroll
    for (int i = 0; i < EW_CHUNK / 256; i++) {
        int e = e0 + i * 256 + threadIdx.x;
        if (e < N_EDGES) atomicAdd(&hist[ei[N_EDGES + e] >> BSHIFT], 1);
    }
    __syncthreads();
    for (int i = threadIdx.x; i < NBUCK; i += 256)
        if (hist[i]) atomicAdd(&bcnt[i], hist[i]);
}

// ---------- CSR build, stage 2: bucket base scan (196 values, one block) ----------
__global__ __launch_bounds__(256) void scan_bucket(
    const int* __restrict__ bcnt, int* __restrict__ bbase, int* __restrict__ gcursor)
{
    __shared__ int sh[256];
    int t = threadIdx.x;
    int v = (t < NBUCK) ? bcnt[t] : 0;
    sh[t] = v;
    __syncthreads();
    for (int off = 1; off < 256; off <<= 1) {
        int u = (t >= off) ? sh[t - off] : 0;
        __syncthreads();
        sh[t] += u;
        __syncthreads();
    }
    if (t < NBUCK) { bbase[t] = sh[t] - v; gcursor[t] = sh[t] - v; }
}

// ---------- CSR build, stage 3: scatter edges into bucket-ordered array ----------
__global__ __launch_bounds__(256) void bucket_scatter(
    const int* __restrict__ ei, int* __restrict__ gcursor, int2* __restrict__ bedge)
{
    __shared__ int hist[NBUCK];
    __shared__ int base[NBUCK];
    for (int i = threadIdx.x; i < NBUCK; i += 256) hist[i] = 0;
    __syncthreads();
    int e0 = blockIdx.x * EW_CHUNK;
    #pragma unroll
    for (int i = 0; i < EW_CHUNK / 256; i++) {
        int e = e0 + i * 256 + threadIdx.x;
        if (e < N_EDGES) atomicAdd(&hist[ei[N_EDGES + e] >> BSHIFT], 1);
    }
    __syncthreads();
    for (int i = threadIdx.x; i < NBUCK; i += 256)
        base[i] = hist[i] ? atomicAdd(&gcursor[i], hist[i]) : 0;
    __syncthreads();
    for (int i = threadIdx.x; i < NBUCK; i += 256) hist[i] = 0;
    __syncthreads();
    #pragma unroll
    for (int i = 0; i < EW_CHUNK / 256; i++) {
        int e = e0 + i * 256 + threadIdx.x;
        if (e < N_EDGES) {
            int src = ei[e];
            int dst = ei[N_EDGES + e];
            int b = dst >> BSHIFT;
            int pos = base[b] + atomicAdd(&hist[b], 1);
            bedge[pos] = make_int2(src, dst);
        }
    }
}

// ---------- CSR build, stage 4: one WG per bucket ----------
// LDS histogram of the bucket's 512 dst -> in-block scan -> row_ptr + cursors
// -> place edges. Replaces the old global deg histogram + 3 scan kernels.
__global__ __launch_bounds__(256) void csr_from_buckets(
    const int2* __restrict__ bedge, const int* __restrict__ bbase,
    const int* __restrict__ bcnt, int* __restrict__ row_ptr,
    int* __restrict__ csr_src)
{
    __shared__ int cur[BUCKET_NODES];   // 512
    __shared__ int psum[256];
    const int b = blockIdx.x;
    const int dst0 = b << BSHIFT;
    const int t = threadIdx.x;

    for (int i = t; i < BUCKET_NODES; i += 256) cur[i] = 0;
    __syncthreads();

    const int beg = bbase[b], cnt = bcnt[b];
    for (int i = t; i < cnt; i += 256)
        atomicAdd(&cur[bedge[beg + i].y - dst0], 1);
    __syncthreads();

    // block scan over 512 (thread t owns 2t, 2t+1)
    int a0 = cur[2 * t], a1 = cur[2 * t + 1];
    int pair = a0 + a1;
    psum[t] = pair;
    __syncthreads();
    for (int off = 1; off < 256; off <<= 1) {
        int u = (t >= off) ? psum[t - off] : 0;
        __syncthreads();
        psum[t] += u;
        __syncthreads();
    }
    int ex = psum[t] - pair;            // exclusive prefix of this pair

    // write row_ptr + init cursors (global positions)
    int d0 = dst0 + 2 * t, d1 = d0 + 1;
    int g0 = beg + ex, g1 = beg + ex + a0;
    if (d0 < N_NODES) row_ptr[d0] = g0;
    if (d1 < N_NODES) row_ptr[d1] = g1;
    if (b == gridDim.x - 1 && t == 255) row_ptr[N_NODES] = beg + psum[255];
    cur[2 * t] = g0;
    cur[2 * t + 1] = g1;
    __syncthreads();

    for (int i = t; i < cnt; i += 256) {
        int2 ed = bedge[beg + i];
        int pos = atomicAdd(&cur[ed.y - dst0], 1);
        csr_src[pos] = ed.x;
    }
}

// ---------- fused attention: wave per dst, 4 edges/iter, float4 features ----------
__global__ __launch_bounds__(256) void attn_fused(
    const int* __restrict__ row_ptr, const int* __restrict__ csr_src,
    const float* __restrict__ q, const float* __restrict__ k,
    const float* __restrict__ v, const float* __restrict__ skip,
    float* __restrict__ hout, int do_relu)
{
    int n = blockIdx.x * 4 + (threadIdx.x >> 6);
    if (n >= N_NODES) return;
    int lane = threadIdx.x & 63;
    int g = lane >> 4;
    int t = lane & 15;
    int beg = row_ptr[n], end = row_ptr[n + 1];

    float4 qf = *(const float4*)&q[(size_t)n * HDIM + t * 4];
    float m = -1e30f, s = 0.f;
    float4 acc = make_float4(0.f, 0.f, 0.f, 0.f);

    for (int i = beg; i < end; i += 4) {
        int e = i + g;
        bool valid = (e < end);
        int src = csr_src[valid ? e : beg];
        float4 kf = *(const float4*)&k[(size_t)src * HDIM + t * 4];
        float4 vf = *(const float4*)&v[(size_t)src * HDIM + t * 4];
        float p = qf.x * kf.x + qf.y * kf.y + qf.z * kf.z + qf.w * kf.w;
        p += __shfl_xor(p, 1, 64);
        p += __shfl_xor(p, 2, 64);
        p += __shfl_xor(p, 4, 64);
        p += __shfl_xor(p, 8, 64);
        float a = valid ? p * 0.125f : -INFINITY;
        float mn = fmaxf(m, a);
        float sc = __expf(m - mn);
        float ew = __expf(a - mn);
        s = s * sc + ew;
        acc.x = acc.x * sc + ew * vf.x;
        acc.y = acc.y * sc + ew * vf.y;
        acc.z = acc.z * sc + ew * vf.z;
        acc.w = acc.w * sc + ew * vf.w;
        m = mn;
    }

    #pragma unroll
    for (int off = 16; off <= 32; off <<= 1) {
        float m2 = __shfl_xor(m, off, 64);
        float s2 = __shfl_xor(s, off, 64);
        float ax = __shfl_xor(acc.x, off, 64);
        float ay = __shfl_xor(acc.y, off, 64);
        float az = __shfl_xor(acc.z, off, 64);
        float aw = __shfl_xor(acc.w, off, 64);
        float mn = fmaxf(m, m2);
        float c1 = __expf(m - mn);
        float c2 = __expf(m2 - mn);
        s = s * c1 + s2 * c2;
        acc.x = acc.x * c1 + ax * c2;
        acc.y = acc.y * c1 + ay * c2;
        acc.z = acc.z * c1 + az * c2;
        acc.w = acc.w * c1 + aw * c2;
        m = mn;
    }

    if (g == 0) {
        float inv = (s > 0.f) ? (1.f / s) : 0.f;
        float4 sk4 = *(const float4*)&skip[(size_t)n * HDIM + t * 4];
        float4 val;
        val.x = acc.x * inv + sk4.x;
        val.y = acc.y * inv + sk4.y;
        val.z = acc.z * inv + sk4.z;
        val.w = acc.w * inv + sk4.w;
        if (do_relu) {
            val.x = fmaxf(val.x, 0.f);
            val.y = fmaxf(val.y, 0.f);
            val.z = fmaxf(val.z, 0.f);
            val.w = fmaxf(val.w, 0.f);
        }
        *(float4*)&hout[(size_t)n * HDIM + t * 4] = val;
    }
}

// ---------- mean pool: run-length accumulate (batch sorted) ----------
__global__ __launch_bounds__(256) void pool_kernel(
    const float* __restrict__ h, const int* __restrict__ batch,
    float* __restrict__ sums, float* __restrict__ cnt)
{
    int wid = blockIdx.x * 4 + (threadIdx.x >> 6);
    int n0 = wid * 64;
    if (n0 >= N_NODES) return;
    int lane = threadIdx.x & 63;
    int nend = min(n0 + 64, N_NODES);
    float acc = 0.f;
    int b_cur = batch[n0];
    int run = 0;
    for (int n = n0; n < nend; n++) {
        int b = batch[n];
        if (b != b_cur) {
            atomicAdd(&sums[b_cur * HDIM + lane], acc);
            if (lane == 0) atomicAdd(&cnt[b_cur], (float)run);
            acc = 0.f; run = 0; b_cur = b;
        }
        acc += h[(size_t)n * HDIM + lane];
        run++;
    }
    atomicAdd(&sums[b_cur * HDIM + lane], acc);
    if (lane == 0) atomicAdd(&cnt[b_cur], (float)run);
}

// ---------- head ----------
__global__ void head_kernel(
    const float* __restrict__ sums, const float* __restrict__ cnt,
    const float* __restrict__ Wl, const float* __restrict__ bl,
    float* __restrict__ out)
{
    int tid = threadIdx.x;
    if (tid >= NB * NC) return;
    int b = tid / NC, c = tid % NC;
    float cc = fmaxf(cnt[b], 1.0f);
    float acc = bl[c];
    #pragma unroll
    for (int f = 0; f < HDIM; f++)
        acc += (sums[b * HDIM + f] / cc) * Wl[c * HDIM + f];
    out[tid] = acc;
}

extern "C" void kernel_launch(void* const* d_in, const int* in_sizes, int n_in,
                              void* d_out, int out_size, void* d_ws, size_t ws_size,
                              hipStream_t stream)
{
    const float* x     = (const float*)d_in[0];
    const int*   ei    = (const int*)d_in[1];
    const int*   batch = (const int*)d_in[2];

    const float* W[3][4];
    const float* B[3][4];
    for (int l = 0; l < 3; l++)
        for (int j = 0; j < 4; j++) {
            W[l][j] = (const float*)d_in[3 + l * 8 + j * 2];
            B[l][j] = (const float*)d_in[3 + l * 8 + j * 2 + 1];
        }
    const float* Wl = (const float*)d_in[27];
    const float* bl = (const float*)d_in[28];
    float* out = (float*)d_out;

    const size_t NF = (size_t)N_NODES * HDIM;
    char* w = (char*)d_ws;
    float* h       = (float*)w;  w += NF * 4;
    float* q       = (float*)w;  w += NF * 4;
    float* kbuf    = (float*)w;  w += NF * 4;
    float* v       = (float*)w;  w += NF * 4;
    float* skip    = (float*)w;  w += NF * 4;
    int*   csr_src = (int*)w;    w += (size_t)N_EDGES * 4;
    int2*  bedge   = (int2*)w;   w += (size_t)N_EDGES * 8;
    int*   row_ptr = (int*)w;    w += (size_t)(N_NODES + 1) * 4;
    int*   bcnt    = (int*)w;    w += (size_t)NBUCK * 4;
    int*   bbase   = (int*)w;    w += (size_t)NBUCK * 4;
    int*   gcursor = (int*)w;    w += (size_t)NBUCK * 4;
    float* sums    = (float*)w;  w += (size_t)NB * HDIM * 4;
    float* cnt     = (float*)w;  w += (size_t)NB * 4;

    const int gemm_gx = (N_NODES + 63) / 64;
    const int node_gx = (N_NODES + 3) / 4;
    const int pool_gx = (N_NODES + 64 * 4 - 1) / (64 * 4);

    // ----- CSR build via LDS-staged counting sort (once; shared by all layers) -----
    hipMemsetAsync(bcnt, 0, (size_t)NBUCK * 4, stream);
    count_bucket<<<EW_GRID, 256, 0, stream>>>(ei, bcnt);
    scan_bucket<<<1, 256, 0, stream>>>(bcnt, bbase, gcursor);
    bucket_scatter<<<EW_GRID, 256, 0, stream>>>(ei, gcursor, bedge);
    csr_from_buckets<<<NBUCK, 256, 0, stream>>>(bedge, bbase, bcnt, row_ptr, csr_src);

    for (int l = 0; l < 3; l++) {
        if (l == 0) {
            qkvs_gemm_f<F_IN><<<gemm_gx, 256, 0, stream>>>(
                x, W[0][0], B[0][0], W[0][1], B[0][1],
                   W[0][2], B[0][2], W[0][3], B[0][3], q, kbuf, v, skip);
        } else {
            qkvs_gemm_f<HDIM><<<gemm_gx, 256, 0, stream>>>(
                h, W[l][0], B[l][0], W[l][1], B[l][1],
                   W[l][2], B[l][2], W[l][3], B[l][3], q, kbuf, v, skip);
        }
        attn_fused<<<node_gx, 256, 0, stream>>>(
            row_ptr, csr_src, q, kbuf, v, skip, h, l < 2 ? 1 : 0);
    }

    hipMemsetAsync(sums, 0, (size_t)NB * HDIM * 4, stream);
    hipMemsetAsync(cnt,  0, (size_t)NB * 4, stream);
    pool_kernel<<<pool_gx, 256, 0, stream>>>(h, batch, sums, cnt);
    head_kernel<<<1, 640, 0, stream>>>(sums, cnt, Wl, bl, out);
}

// Round 11
// 677.935 us; speedup vs baseline: 1.3419x; 1.0178x over previous
//
#include <hip/hip_runtime.h>
#include <math.h>

#define N_NODES 100000
#define N_EDGES 1600000
#define NB 64
#define F_IN 128
#define HDIM 64
#define NC 10

#define BSHIFT 9
#define BUCKET_NODES (1 << BSHIFT)                          // 512
#define NBUCK ((N_NODES + BUCKET_NODES - 1) >> BSHIFT)      // 196
#define EW_CHUNK 4096
#define EW_GRID ((N_EDGES + EW_CHUNK - 1) / EW_CHUNK)       // 391

// ---------- fused q/k/v/skip GEMM (r6 structure: X staged once, full-W per mat) ----------
// 64-row tile, 4x4 thread tile, grid = ceil(N/64). Known-good: 130us l0
// (~6% above its ds_read_b128 throughput roofline; bigger tiles lose to occupancy).
template<int K>
__global__ __launch_bounds__(256) void qkvs_gemm_f(
    const float* __restrict__ xin,
    const float* __restrict__ Wq, const float* __restrict__ bq,
    const float* __restrict__ Wk, const float* __restrict__ bk,
    const float* __restrict__ Wv, const float* __restrict__ bv,
    const float* __restrict__ Ws, const float* __restrict__ bs,
    float* __restrict__ q, float* __restrict__ k,
    float* __restrict__ v, float* __restrict__ sk)
{
    __shared__ float Xs[K][68];    // transposed: Xs[k][row]
    __shared__ float Wt[K][68];    // transposed: Wt[k][col], full K for one mat

    const int row0 = blockIdx.x * 64;
    const int tid  = threadIdx.x;
    const int tc   = tid & 15;     // col group (4 cols each)
    const int tr   = tid >> 4;     // row group (4 rows each)
    const int lrow = tid >> 2;     // 0..63
    const int lk   = (tid & 3) * 8;

    // stage full X tile (64 rows x K) transposed
    for (int k0 = 0; k0 < K; k0 += 32) {
        int grow = row0 + lrow;
        float tmp[8];
        if (grow < N_NODES) {
            const float* p = xin + (size_t)grow * K + k0 + lk;
            float4 a = *(const float4*)p;
            float4 c = *(const float4*)(p + 4);
            tmp[0]=a.x; tmp[1]=a.y; tmp[2]=a.z; tmp[3]=a.w;
            tmp[4]=c.x; tmp[5]=c.y; tmp[6]=c.z; tmp[7]=c.w;
        } else {
            #pragma unroll
            for (int i = 0; i < 8; i++) tmp[i] = 0.f;
        }
        #pragma unroll
        for (int i = 0; i < 8; i++) Xs[k0 + lk + i][lrow] = tmp[i];
    }

    const float* Wm[4] = {Wq, Wk, Wv, Ws};
    const float* Bm[4] = {bq, bk, bv, bs};
    float*       Om[4] = {q, k, v, sk};

    for (int mat = 0; mat < 4; mat++) {
        if (mat) __syncthreads();          // protect Wt from previous compute
        // stage full W (64 out-cols x K) transposed
        for (int k0 = 0; k0 < K; k0 += 32) {
            const float* pw = Wm[mat] + (size_t)lrow * K + k0 + lk;
            float4 a = *(const float4*)pw;
            float4 c = *(const float4*)(pw + 4);
            float wt[8] = {a.x, a.y, a.z, a.w, c.x, c.y, c.z, c.w};
            #pragma unroll
            for (int i = 0; i < 8; i++) Wt[k0 + lk + i][lrow] = wt[i];
        }
        __syncthreads();                   // covers Xs (first mat) + Wt

        float acc[4][4] = {};
        #pragma unroll 8
        for (int kk = 0; kk < K; kk++) {
            float4 xf = *(const float4*)&Xs[kk][tr * 4];
            float4 wf = *(const float4*)&Wt[kk][tc * 4];
            float xa[4] = {xf.x, xf.y, xf.z, xf.w};
            float wa[4] = {wf.x, wf.y, wf.z, wf.w};
            #pragma unroll
            for (int i = 0; i < 4; i++)
                #pragma unroll
                for (int j = 0; j < 4; j++)
                    acc[i][j] += xa[i] * wa[j];
        }

        float4 bias = *(const float4*)&Bm[mat][tc * 4];
        float ba[4] = {bias.x, bias.y, bias.z, bias.w};
        float* out = Om[mat];
        #pragma unroll
        for (int i = 0; i < 4; i++) {
            int grow = row0 + tr * 4 + i;
            if (grow < N_NODES) {
                float4 r;
                r.x = acc[i][0] + ba[0];
                r.y = acc[i][1] + ba[1];
                r.z = acc[i][2] + ba[2];
                r.w = acc[i][3] + ba[3];
                *(float4*)&out[(size_t)grow * HDIM + tc * 4] = r;
            }
        }
    }
}

// ---------- CSR build, stage 1: per-bucket edge counts (LDS hist only) ----------
__global__ __launch_bounds__(256) void count_bucket(
    const int* __restrict__ ei, int* __restrict__ bcnt)
{
    __shared__ int hist[NBUCK];
    for (int i = threadIdx.x; i < NBUCK; i += 256) hist[i] = 0;
    __syncthreads();
    int e0 = blockIdx.x * EW_CHUNK;
    #pragma unroll
    for (int i = 0; i < EW_CHUNK / 256; i++) {
        int e = e0 + i * 256 + threadIdx.x;
        if (e < N_EDGES) atomicAdd(&hist[ei[N_EDGES + e] >> BSHIFT], 1);
    }
    __syncthreads();
    for (int i = threadIdx.x; i < NBUCK; i += 256)
        if (hist[i]) atomicAdd(&bcnt[i], hist[i]);
}

// ---------- CSR build, stage 2: bucket base scan (196 values, one block) ----------
__global__ __launch_bounds__(256) void scan_bucket(
    const int* __restrict__ bcnt, int* __restrict__ bbase, int* __restrict__ gcursor)
{
    __shared__ int sh[256];
    int t = threadIdx.x;
    int v = (t < NBUCK) ? bcnt[t] : 0;
    sh[t] = v;
    __syncthreads();
    for (int off = 1; off < 256; off <<= 1) {
        int u = (t >= off) ? sh[t - off] : 0;
        __syncthreads();
        sh[t] += u;
        __syncthreads();
    }
    if (t < NBUCK) { bbase[t] = sh[t] - v; gcursor[t] = sh[t] - v; }
}

// ---------- CSR build, stage 3: scatter packed edges into bucket order ----------
// packed entry: (dst_local << 17) | src   (src < 2^17, dst_local < 2^9)
__global__ __launch_bounds__(256) void bucket_scatter(
    const int* __restrict__ ei, int* __restrict__ gcursor, int* __restrict__ bedge)
{
    __shared__ int hist[NBUCK];
    __shared__ int base[NBUCK];
    for (int i = threadIdx.x; i < NBUCK; i += 256) hist[i] = 0;
    __syncthreads();
    int e0 = blockIdx.x * EW_CHUNK;
    #pragma unroll
    for (int i = 0; i < EW_CHUNK / 256; i++) {
        int e = e0 + i * 256 + threadIdx.x;
        if (e < N_EDGES) atomicAdd(&hist[ei[N_EDGES + e] >> BSHIFT], 1);
    }
    __syncthreads();
    for (int i = threadIdx.x; i < NBUCK; i += 256)
        base[i] = hist[i] ? atomicAdd(&gcursor[i], hist[i]) : 0;
    __syncthreads();
    for (int i = threadIdx.x; i < NBUCK; i += 256) hist[i] = 0;
    __syncthreads();
    #pragma unroll
    for (int i = 0; i < EW_CHUNK / 256; i++) {
        int e = e0 + i * 256 + threadIdx.x;
        if (e < N_EDGES) {
            int src = ei[e];
            int dst = ei[N_EDGES + e];
            int b = dst >> BSHIFT;
            int pos = base[b] + atomicAdd(&hist[b], 1);
            bedge[pos] = ((dst & (BUCKET_NODES - 1)) << 17) | src;
        }
    }
}

// ---------- CSR build, stage 4: one WG per bucket ----------
// LDS histogram of the bucket's 512 dst -> in-block scan -> row_ptr + cursors
// -> place edges.
__global__ __launch_bounds__(256) void csr_from_buckets(
    const int* __restrict__ bedge, const int* __restrict__ bbase,
    const int* __restrict__ bcnt, int* __restrict__ row_ptr,
    int* __restrict__ csr_src)
{
    __shared__ int cur[BUCKET_NODES];   // 512
    __shared__ int psum[256];
    const int b = blockIdx.x;
    const int dst0 = b << BSHIFT;
    const int t = threadIdx.x;

    for (int i = t; i < BUCKET_NODES; i += 256) cur[i] = 0;
    __syncthreads();

    const int beg = bbase[b], cnt = bcnt[b];
    for (int i = t; i < cnt; i += 256)
        atomicAdd(&cur[bedge[beg + i] >> 17], 1);
    __syncthreads();

    // block scan over 512 (thread t owns 2t, 2t+1)
    int a0 = cur[2 * t], a1 = cur[2 * t + 1];
    int pair = a0 + a1;
    psum[t] = pair;
    __syncthreads();
    for (int off = 1; off < 256; off <<= 1) {
        int u = (t >= off) ? psum[t - off] : 0;
        __syncthreads();
        psum[t] += u;
        __syncthreads();
    }
    int ex = psum[t] - pair;            // exclusive prefix of this pair

    int d0 = dst0 + 2 * t, d1 = d0 + 1;
    int g0 = beg + ex, g1 = beg + ex + a0;
    if (d0 < N_NODES) row_ptr[d0] = g0;
    if (d1 < N_NODES) row_ptr[d1] = g1;
    if (b == gridDim.x - 1 && t == 255) row_ptr[N_NODES] = beg + psum[255];
    cur[2 * t] = g0;
    cur[2 * t + 1] = g1;
    __syncthreads();

    for (int i = t; i < cnt; i += 256) {
        int ed = bedge[beg + i];
        int pos = atomicAdd(&cur[ed >> 17], 1);
        csr_src[pos] = ed & 0x1FFFF;
    }
}

// ---------- fused attention: wave per dst, 8 edges/iter, 8-lane feature groups ----------
// lane = g*8 + t : g = edge slot (0..7), t = feature octet (features 8t..8t+7)
__global__ __launch_bounds__(256) void attn_fused(
    const int* __restrict__ row_ptr, const int* __restrict__ csr_src,
    const float* __restrict__ q, const float* __restrict__ k,
    const float* __restrict__ v, const float* __restrict__ skip,
    float* __restrict__ hout, int do_relu)
{
    int n = blockIdx.x * 4 + (threadIdx.x >> 6);
    if (n >= N_NODES) return;
    int lane = threadIdx.x & 63;
    int g = lane >> 3;
    int t = lane & 7;
    int beg = row_ptr[n], end = row_ptr[n + 1];

    const float* qrow = &q[(size_t)n * HDIM + t * 8];
    float4 qa = *(const float4*)qrow;
    float4 qb = *(const float4*)(qrow + 4);
    float m = -1e30f, s = 0.f;
    float4 aca = make_float4(0.f, 0.f, 0.f, 0.f);
    float4 acb = make_float4(0.f, 0.f, 0.f, 0.f);

    for (int i = beg; i < end; i += 8) {
        int e = i + g;
        bool valid = (e < end);
        int src = csr_src[valid ? e : beg];
        const float* krow = &k[(size_t)src * HDIM + t * 8];
        const float* vrow = &v[(size_t)src * HDIM + t * 8];
        float4 ka = *(const float4*)krow;
        float4 kb = *(const float4*)(krow + 4);
        float4 va = *(const float4*)vrow;
        float4 vb = *(const float4*)(vrow + 4);
        float p = qa.x*ka.x + qa.y*ka.y + qa.z*ka.z + qa.w*ka.w
                + qb.x*kb.x + qb.y*kb.y + qb.z*kb.z + qb.w*kb.w;
        p += __shfl_xor(p, 1, 64);
        p += __shfl_xor(p, 2, 64);
        p += __shfl_xor(p, 4, 64);
        float a = valid ? p * 0.125f : -INFINITY;
        float mn = fmaxf(m, a);
        float sc = __expf(m - mn);
        float ew = __expf(a - mn);
        s = s * sc + ew;
        aca.x = aca.x * sc + ew * va.x;
        aca.y = aca.y * sc + ew * va.y;
        aca.z = aca.z * sc + ew * va.z;
        aca.w = aca.w * sc + ew * va.w;
        acb.x = acb.x * sc + ew * vb.x;
        acb.y = acb.y * sc + ew * vb.y;
        acb.z = acb.z * sc + ew * vb.z;
        acb.w = acb.w * sc + ew * vb.w;
        m = mn;
    }

    // merge the 8 group-local softmax states (offsets 8,16,32)
    #pragma unroll
    for (int off = 8; off <= 32; off <<= 1) {
        float m2 = __shfl_xor(m, off, 64);
        float s2 = __shfl_xor(s, off, 64);
        float x0 = __shfl_xor(aca.x, off, 64);
        float x1 = __shfl_xor(aca.y, off, 64);
        float x2 = __shfl_xor(aca.z, off, 64);
        float x3 = __shfl_xor(aca.w, off, 64);
        float x4 = __shfl_xor(acb.x, off, 64);
        float x5 = __shfl_xor(acb.y, off, 64);
        float x6 = __shfl_xor(acb.z, off, 64);
        float x7 = __shfl_xor(acb.w, off, 64);
        float mn = fmaxf(m, m2);
        float c1 = __expf(m - mn);
        float c2 = __expf(m2 - mn);
        s = s * c1 + s2 * c2;
        aca.x = aca.x * c1 + x0 * c2;
        aca.y = aca.y * c1 + x1 * c2;
        aca.z = aca.z * c1 + x2 * c2;
        aca.w = aca.w * c1 + x3 * c2;
        acb.x = acb.x * c1 + x4 * c2;
        acb.y = acb.y * c1 + x5 * c2;
        acb.z = acb.z * c1 + x6 * c2;
        acb.w = acb.w * c1 + x7 * c2;
        m = mn;
    }

    if (g == 0) {
        float inv = (s > 0.f) ? (1.f / s) : 0.f;
        const float* skrow = &skip[(size_t)n * HDIM + t * 8];
        float4 s0 = *(const float4*)skrow;
        float4 s1 = *(const float4*)(skrow + 4);
        float4 o0, o1;
        o0.x = aca.x * inv + s0.x;
        o0.y = aca.y * inv + s0.y;
        o0.z = aca.z * inv + s0.z;
        o0.w = aca.w * inv + s0.w;
        o1.x = acb.x * inv + s1.x;
        o1.y = acb.y * inv + s1.y;
        o1.z = acb.z * inv + s1.z;
        o1.w = acb.w * inv + s1.w;
        if (do_relu) {
            o0.x = fmaxf(o0.x, 0.f); o0.y = fmaxf(o0.y, 0.f);
            o0.z = fmaxf(o0.z, 0.f); o0.w = fmaxf(o0.w, 0.f);
            o1.x = fmaxf(o1.x, 0.f); o1.y = fmaxf(o1.y, 0.f);
            o1.z = fmaxf(o1.z, 0.f); o1.w = fmaxf(o1.w, 0.f);
        }
        float* orow = &hout[(size_t)n * HDIM + t * 8];
        *(float4*)orow = o0;
        *(float4*)(orow + 4) = o1;
    }
}

// ---------- mean pool: run-length accumulate (batch sorted) ----------
__global__ __launch_bounds__(256) void pool_kernel(
    const float* __restrict__ h, const int* __restrict__ batch,
    float* __restrict__ sums, float* __restrict__ cnt)
{
    int wid = blockIdx.x * 4 + (threadIdx.x >> 6);
    int n0 = wid * 64;
    if (n0 >= N_NODES) return;
    int lane = threadIdx.x & 63;
    int nend = min(n0 + 64, N_NODES);
    float acc = 0.f;
    int b_cur = batch[n0];
    int run = 0;
    for (int n = n0; n < nend; n++) {
        int b = batch[n];
        if (b != b_cur) {
            atomicAdd(&sums[b_cur * HDIM + lane], acc);
            if (lane == 0) atomicAdd(&cnt[b_cur], (float)run);
            acc = 0.f; run = 0; b_cur = b;
        }
        acc += h[(size_t)n * HDIM + lane];
        run++;
    }
    atomicAdd(&sums[b_cur * HDIM + lane], acc);
    if (lane == 0) atomicAdd(&cnt[b_cur], (float)run);
}

// ---------- head ----------
__global__ void head_kernel(
    const float* __restrict__ sums, const float* __restrict__ cnt,
    const float* __restrict__ Wl, const float* __restrict__ bl,
    float* __restrict__ out)
{
    int tid = threadIdx.x;
    if (tid >= NB * NC) return;
    int b = tid / NC, c = tid % NC;
    float cc = fmaxf(cnt[b], 1.0f);
    float acc = bl[c];
    #pragma unroll
    for (int f = 0; f < HDIM; f++)
        acc += (sums[b * HDIM + f] / cc) * Wl[c * HDIM + f];
    out[tid] = acc;
}

extern "C" void kernel_launch(void* const* d_in, const int* in_sizes, int n_in,
                              void* d_out, int out_size, void* d_ws, size_t ws_size,
                              hipStream_t stream)
{
    const float* x     = (const float*)d_in[0];
    const int*   ei    = (const int*)d_in[1];
    const int*   batch = (const int*)d_in[2];

    const float* W[3][4];
    const float* B[3][4];
    for (int l = 0; l < 3; l++)
        for (int j = 0; j < 4; j++) {
            W[l][j] = (const float*)d_in[3 + l * 8 + j * 2];
            B[l][j] = (const float*)d_in[3 + l * 8 + j * 2 + 1];
        }
    const float* Wl = (const float*)d_in[27];
    const float* bl = (const float*)d_in[28];
    float* out = (float*)d_out;

    const size_t NF = (size_t)N_NODES * HDIM;
    char* w = (char*)d_ws;
    float* h       = (float*)w;  w += NF * 4;
    float* q       = (float*)w;  w += NF * 4;
    float* kbuf    = (float*)w;  w += NF * 4;
    float* v       = (float*)w;  w += NF * 4;
    float* skip    = (float*)w;  w += NF * 4;
    int*   csr_src = (int*)w;    w += (size_t)N_EDGES * 4;
    int*   bedge   = (int*)w;    w += (size_t)N_EDGES * 4;
    int*   row_ptr = (int*)w;    w += (size_t)(N_NODES + 1) * 4;
    int*   bcnt    = (int*)w;    w += (size_t)NBUCK * 4;
    int*   bbase   = (int*)w;    w += (size_t)NBUCK * 4;
    int*   gcursor = (int*)w;    w += (size_t)NBUCK * 4;
    float* sums    = (float*)w;  w += (size_t)NB * HDIM * 4;
    float* cnt     = (float*)w;  w += (size_t)NB * 4;

    const int gemm_gx = (N_NODES + 63) / 64;
    const int node_gx = (N_NODES + 3) / 4;
    const int pool_gx = (N_NODES + 64 * 4 - 1) / (64 * 4);

    // ----- CSR build via LDS-staged counting sort (once; shared by all layers) -----
    hipMemsetAsync(bcnt, 0, (size_t)NBUCK * 4, stream);
    count_bucket<<<EW_GRID, 256, 0, stream>>>(ei, bcnt);
    scan_bucket<<<1, 256, 0, stream>>>(bcnt, bbase, gcursor);
    bucket_scatter<<<EW_GRID, 256, 0, stream>>>(ei, gcursor, bedge);
    csr_from_buckets<<<NBUCK, 256, 0, stream>>>(bedge, bbase, bcnt, row_ptr, csr_src);

    for (int l = 0; l < 3; l++) {
        if (l == 0) {
            qkvs_gemm_f<F_IN><<<gemm_gx, 256, 0, stream>>>(
                x, W[0][0], B[0][0], W[0][1], B[0][1],
                   W[0][2], B[0][2], W[0][3], B[0][3], q, kbuf, v, skip);
        } else {
            qkvs_gemm_f<HDIM><<<gemm_gx, 256, 0, stream>>>(
                h, W[l][0], B[l][0], W[l][1], B[l][1],
                   W[l][2], B[l][2], W[l][3], B[l][3], q, kbuf, v, skip);
        }
        attn_fused<<<node_gx, 256, 0, stream>>>(
            row_ptr, csr_src, q, kbuf, v, skip, h, l < 2 ? 1 : 0);
    }

    hipMemsetAsync(sums, 0, (size_t)NB * HDIM * 4, stream);
    hipMemsetAsync(cnt,  0, (size_t)NB * 4, stream);
    pool_kernel<<<pool_gx, 256, 0, stream>>>(h, batch, sums, cnt);
    head_kernel<<<1, 640, 0, stream>>>(sums, cnt, Wl, bl, out);
}

// Round 12
// 545.774 us; speedup vs baseline: 1.6668x; 1.2422x over previous
//
#include <hip/hip_runtime.h>
#include <math.h>

#define N_NODES 100000
#define N_EDGES 1600000
#define NB 64
#define F_IN 128
#define HDIM 64
#define NC 10

#define BSHIFT 9
#define BUCKET_NODES (1 << BSHIFT)                          // 512
#define NBUCK ((N_NODES + BUCKET_NODES - 1) >> BSHIFT)      // 196
#define EW_CHUNK 4096
#define EW_GRID ((N_EDGES + EW_CHUNK - 1) / EW_CHUNK)       // 391

// ---------- bf16 helpers ----------
__device__ __forceinline__ unsigned short f2bf(float f) {
    unsigned u = __float_as_uint(f);
    u += 0x7FFFu + ((u >> 16) & 1u);    // round to nearest even
    return (unsigned short)(u >> 16);
}
__device__ __forceinline__ unsigned pack2bf(float a, float b) {
    return (unsigned)f2bf(a) | ((unsigned)f2bf(b) << 16);
}

// ---------- fused q/k/v/skip GEMM (r6 structure; k,v emitted as bf16) ----------
// 64-row tile, 4x4 thread tile, grid = ceil(N/64). Known-good: 130us l0.
template<int K>
__global__ __launch_bounds__(256) void qkvs_gemm_f(
    const float* __restrict__ xin,
    const float* __restrict__ Wq, const float* __restrict__ bq,
    const float* __restrict__ Wk, const float* __restrict__ bk,
    const float* __restrict__ Wv, const float* __restrict__ bv,
    const float* __restrict__ Ws, const float* __restrict__ bs,
    float* __restrict__ q, unsigned short* __restrict__ k16,
    unsigned short* __restrict__ v16, float* __restrict__ sk)
{
    __shared__ float Xs[K][68];    // transposed: Xs[k][row]
    __shared__ float Wt[K][68];    // transposed: Wt[k][col], full K for one mat

    const int row0 = blockIdx.x * 64;
    const int tid  = threadIdx.x;
    const int tc   = tid & 15;     // col group (4 cols each)
    const int tr   = tid >> 4;     // row group (4 rows each)
    const int lrow = tid >> 2;     // 0..63
    const int lk   = (tid & 3) * 8;

    // stage full X tile (64 rows x K) transposed
    for (int k0 = 0; k0 < K; k0 += 32) {
        int grow = row0 + lrow;
        float tmp[8];
        if (grow < N_NODES) {
            const float* p = xin + (size_t)grow * K + k0 + lk;
            float4 a = *(const float4*)p;
            float4 c = *(const float4*)(p + 4);
            tmp[0]=a.x; tmp[1]=a.y; tmp[2]=a.z; tmp[3]=a.w;
            tmp[4]=c.x; tmp[5]=c.y; tmp[6]=c.z; tmp[7]=c.w;
        } else {
            #pragma unroll
            for (int i = 0; i < 8; i++) tmp[i] = 0.f;
        }
        #pragma unroll
        for (int i = 0; i < 8; i++) Xs[k0 + lk + i][lrow] = tmp[i];
    }

    const float* Wm[4] = {Wq, Wk, Wv, Ws};
    const float* Bm[4] = {bq, bk, bv, bs};

    for (int mat = 0; mat < 4; mat++) {
        if (mat) __syncthreads();          // protect Wt from previous compute
        // stage full W (64 out-cols x K) transposed
        for (int k0 = 0; k0 < K; k0 += 32) {
            const float* pw = Wm[mat] + (size_t)lrow * K + k0 + lk;
            float4 a = *(const float4*)pw;
            float4 c = *(const float4*)(pw + 4);
            float wt[8] = {a.x, a.y, a.z, a.w, c.x, c.y, c.z, c.w};
            #pragma unroll
            for (int i = 0; i < 8; i++) Wt[k0 + lk + i][lrow] = wt[i];
        }
        __syncthreads();                   // covers Xs (first mat) + Wt

        float acc[4][4] = {};
        #pragma unroll 8
        for (int kk = 0; kk < K; kk++) {
            float4 xf = *(const float4*)&Xs[kk][tr * 4];
            float4 wf = *(const float4*)&Wt[kk][tc * 4];
            float xa[4] = {xf.x, xf.y, xf.z, xf.w};
            float wa[4] = {wf.x, wf.y, wf.z, wf.w};
            #pragma unroll
            for (int i = 0; i < 4; i++)
                #pragma unroll
                for (int j = 0; j < 4; j++)
                    acc[i][j] += xa[i] * wa[j];
        }

        float4 bias = *(const float4*)&Bm[mat][tc * 4];
        float ba[4] = {bias.x, bias.y, bias.z, bias.w};
        if (mat == 1 || mat == 2) {
            unsigned short* o16 = (mat == 1) ? k16 : v16;
            #pragma unroll
            for (int i = 0; i < 4; i++) {
                int grow = row0 + tr * 4 + i;
                if (grow < N_NODES) {
                    uint2 w2;
                    w2.x = pack2bf(acc[i][0] + ba[0], acc[i][1] + ba[1]);
                    w2.y = pack2bf(acc[i][2] + ba[2], acc[i][3] + ba[3]);
                    *(uint2*)&o16[(size_t)grow * HDIM + tc * 4] = w2;
                }
            }
        } else {
            float* out = (mat == 0) ? q : sk;
            #pragma unroll
            for (int i = 0; i < 4; i++) {
                int grow = row0 + tr * 4 + i;
                if (grow < N_NODES) {
                    float4 r;
                    r.x = acc[i][0] + ba[0];
                    r.y = acc[i][1] + ba[1];
                    r.z = acc[i][2] + ba[2];
                    r.w = acc[i][3] + ba[3];
                    *(float4*)&out[(size_t)grow * HDIM + tc * 4] = r;
                }
            }
        }
    }
}

// ---------- CSR build, stage 1: per-bucket edge counts (LDS hist only) ----------
__global__ __launch_bounds__(256) void count_bucket(
    const int* __restrict__ ei, int* __restrict__ bcnt)
{
    __shared__ int hist[NBUCK];
    for (int i = threadIdx.x; i < NBUCK; i += 256) hist[i] = 0;
    __syncthreads();
    int e0 = blockIdx.x * EW_CHUNK;
    #pragma unroll
    for (int i = 0; i < EW_CHUNK / 256; i++) {
        int e = e0 + i * 256 + threadIdx.x;
        if (e < N_EDGES) atomicAdd(&hist[ei[N_EDGES + e] >> BSHIFT], 1);
    }
    __syncthreads();
    for (int i = threadIdx.x; i < NBUCK; i += 256)
        if (hist[i]) atomicAdd(&bcnt[i], hist[i]);
}

// ---------- CSR build, stage 2: bucket base scan (196 values, one block) ----------
__global__ __launch_bounds__(256) void scan_bucket(
    const int* __restrict__ bcnt, int* __restrict__ bbase, int* __restrict__ gcursor)
{
    __shared__ int sh[256];
    int t = threadIdx.x;
    int v = (t < NBUCK) ? bcnt[t] : 0;
    sh[t] = v;
    __syncthreads();
    for (int off = 1; off < 256; off <<= 1) {
        int u = (t >= off) ? sh[t - off] : 0;
        __syncthreads();
        sh[t] += u;
        __syncthreads();
    }
    if (t < NBUCK) { bbase[t] = sh[t] - v; gcursor[t] = sh[t] - v; }
}

// ---------- CSR build, stage 3: scatter packed edges into bucket order ----------
// packed entry: (dst_local << 17) | src   (src < 2^17, dst_local < 2^9)
__global__ __launch_bounds__(256) void bucket_scatter(
    const int* __restrict__ ei, int* __restrict__ gcursor, int* __restrict__ bedge)
{
    __shared__ int hist[NBUCK];
    __shared__ int base[NBUCK];
    for (int i = threadIdx.x; i < NBUCK; i += 256) hist[i] = 0;
    __syncthreads();
    int e0 = blockIdx.x * EW_CHUNK;
    #pragma unroll
    for (int i = 0; i < EW_CHUNK / 256; i++) {
        int e = e0 + i * 256 + threadIdx.x;
        if (e < N_EDGES) atomicAdd(&hist[ei[N_EDGES + e] >> BSHIFT], 1);
    }
    __syncthreads();
    for (int i = threadIdx.x; i < NBUCK; i += 256)
        base[i] = hist[i] ? atomicAdd(&gcursor[i], hist[i]) : 0;
    __syncthreads();
    for (int i = threadIdx.x; i < NBUCK; i += 256) hist[i] = 0;
    __syncthreads();
    #pragma unroll
    for (int i = 0; i < EW_CHUNK / 256; i++) {
        int e = e0 + i * 256 + threadIdx.x;
        if (e < N_EDGES) {
            int src = ei[e];
            int dst = ei[N_EDGES + e];
            int b = dst >> BSHIFT;
            int pos = base[b] + atomicAdd(&hist[b], 1);
            bedge[pos] = ((dst & (BUCKET_NODES - 1)) << 17) | src;
        }
    }
}

// ---------- CSR build, stage 4: one WG per bucket ----------
__global__ __launch_bounds__(256) void csr_from_buckets(
    const int* __restrict__ bedge, const int* __restrict__ bbase,
    const int* __restrict__ bcnt, int* __restrict__ row_ptr,
    int* __restrict__ csr_src)
{
    __shared__ int cur[BUCKET_NODES];   // 512
    __shared__ int psum[256];
    const int b = blockIdx.x;
    const int dst0 = b << BSHIFT;
    const int t = threadIdx.x;

    for (int i = t; i < BUCKET_NODES; i += 256) cur[i] = 0;
    __syncthreads();

    const int beg = bbase[b], cnt = bcnt[b];
    for (int i = t; i < cnt; i += 256)
        atomicAdd(&cur[bedge[beg + i] >> 17], 1);
    __syncthreads();

    int a0 = cur[2 * t], a1 = cur[2 * t + 1];
    int pair = a0 + a1;
    psum[t] = pair;
    __syncthreads();
    for (int off = 1; off < 256; off <<= 1) {
        int u = (t >= off) ? psum[t - off] : 0;
        __syncthreads();
        psum[t] += u;
        __syncthreads();
    }
    int ex = psum[t] - pair;            // exclusive prefix of this pair

    int d0 = dst0 + 2 * t, d1 = d0 + 1;
    int g0 = beg + ex, g1 = beg + ex + a0;
    if (d0 < N_NODES) row_ptr[d0] = g0;
    if (d1 < N_NODES) row_ptr[d1] = g1;
    if (b == gridDim.x - 1 && t == 255) row_ptr[N_NODES] = beg + psum[255];
    cur[2 * t] = g0;
    cur[2 * t + 1] = g1;
    __syncthreads();

    for (int i = t; i < cnt; i += 256) {
        int ed = bedge[beg + i];
        int pos = atomicAdd(&cur[ed >> 17], 1);
        csr_src[pos] = ed & 0x1FFFF;
    }
}

// ---------- fused attention: wave per dst, 8 edges/iter, bf16 k/v gathers ----------
// lane = g*8 + t : g = edge slot (0..7), t = feature octet (features 8t..8t+7)
__global__ __launch_bounds__(256) void attn_fused(
    const int* __restrict__ row_ptr, const int* __restrict__ csr_src,
    const float* __restrict__ q, const unsigned short* __restrict__ k16,
    const unsigned short* __restrict__ v16, const float* __restrict__ skip,
    float* __restrict__ hout, int do_relu)
{
    int n = blockIdx.x * 4 + (threadIdx.x >> 6);
    if (n >= N_NODES) return;
    int lane = threadIdx.x & 63;
    int g = lane >> 3;
    int t = lane & 7;
    int beg = row_ptr[n], end = row_ptr[n + 1];

    const float* qrow = &q[(size_t)n * HDIM + t * 8];
    float4 qa = *(const float4*)qrow;
    float4 qb = *(const float4*)(qrow + 4);
    float m = -1e30f, s = 0.f;
    float4 aca = make_float4(0.f, 0.f, 0.f, 0.f);
    float4 acb = make_float4(0.f, 0.f, 0.f, 0.f);

    for (int i = beg; i < end; i += 8) {
        int e = i + g;
        bool valid = (e < end);
        int src = csr_src[valid ? e : beg];
        uint4 ku = *(const uint4*)&k16[(size_t)src * HDIM + t * 8];
        uint4 vu = *(const uint4*)&v16[(size_t)src * HDIM + t * 8];
        float p = qa.x * __uint_as_float(ku.x << 16)
                + qa.y * __uint_as_float(ku.x & 0xFFFF0000u)
                + qa.z * __uint_as_float(ku.y << 16)
                + qa.w * __uint_as_float(ku.y & 0xFFFF0000u)
                + qb.x * __uint_as_float(ku.z << 16)
                + qb.y * __uint_as_float(ku.z & 0xFFFF0000u)
                + qb.z * __uint_as_float(ku.w << 16)
                + qb.w * __uint_as_float(ku.w & 0xFFFF0000u);
        p += __shfl_xor(p, 1, 64);
        p += __shfl_xor(p, 2, 64);
        p += __shfl_xor(p, 4, 64);
        float a = valid ? p * 0.125f : -INFINITY;
        float mn = fmaxf(m, a);
        float sc = __expf(m - mn);
        float ew = __expf(a - mn);
        s = s * sc + ew;
        aca.x = aca.x * sc + ew * __uint_as_float(vu.x << 16);
        aca.y = aca.y * sc + ew * __uint_as_float(vu.x & 0xFFFF0000u);
        aca.z = aca.z * sc + ew * __uint_as_float(vu.y << 16);
        aca.w = aca.w * sc + ew * __uint_as_float(vu.y & 0xFFFF0000u);
        acb.x = acb.x * sc + ew * __uint_as_float(vu.z << 16);
        acb.y = acb.y * sc + ew * __uint_as_float(vu.z & 0xFFFF0000u);
        acb.z = acb.z * sc + ew * __uint_as_float(vu.w << 16);
        acb.w = acb.w * sc + ew * __uint_as_float(vu.w & 0xFFFF0000u);
        m = mn;
    }

    // merge the 8 group-local softmax states (offsets 8,16,32)
    #pragma unroll
    for (int off = 8; off <= 32; off <<= 1) {
        float m2 = __shfl_xor(m, off, 64);
        float s2 = __shfl_xor(s, off, 64);
        float x0 = __shfl_xor(aca.x, off, 64);
        float x1 = __shfl_xor(aca.y, off, 64);
        float x2 = __shfl_xor(aca.z, off, 64);
        float x3 = __shfl_xor(aca.w, off, 64);
        float x4 = __shfl_xor(acb.x, off, 64);
        float x5 = __shfl_xor(acb.y, off, 64);
        float x6 = __shfl_xor(acb.z, off, 64);
        float x7 = __shfl_xor(acb.w, off, 64);
        float mn = fmaxf(m, m2);
        float c1 = __expf(m - mn);
        float c2 = __expf(m2 - mn);
        s = s * c1 + s2 * c2;
        aca.x = aca.x * c1 + x0 * c2;
        aca.y = aca.y * c1 + x1 * c2;
        aca.z = aca.z * c1 + x2 * c2;
        aca.w = aca.w * c1 + x3 * c2;
        acb.x = acb.x * c1 + x4 * c2;
        acb.y = acb.y * c1 + x5 * c2;
        acb.z = acb.z * c1 + x6 * c2;
        acb.w = acb.w * c1 + x7 * c2;
        m = mn;
    }

    if (g == 0) {
        float inv = (s > 0.f) ? (1.f / s) : 0.f;
        const float* skrow = &skip[(size_t)n * HDIM + t * 8];
        float4 s0 = *(const float4*)skrow;
        float4 s1 = *(const float4*)(skrow + 4);
        float4 o0, o1;
        o0.x = aca.x * inv + s0.x;
        o0.y = aca.y * inv + s0.y;
        o0.z = aca.z * inv + s0.z;
        o0.w = aca.w * inv + s0.w;
        o1.x = acb.x * inv + s1.x;
        o1.y = acb.y * inv + s1.y;
        o1.z = acb.z * inv + s1.z;
        o1.w = acb.w * inv + s1.w;
        if (do_relu) {
            o0.x = fmaxf(o0.x, 0.f); o0.y = fmaxf(o0.y, 0.f);
            o0.z = fmaxf(o0.z, 0.f); o0.w = fmaxf(o0.w, 0.f);
            o1.x = fmaxf(o1.x, 0.f); o1.y = fmaxf(o1.y, 0.f);
            o1.z = fmaxf(o1.z, 0.f); o1.w = fmaxf(o1.w, 0.f);
        }
        float* orow = &hout[(size_t)n * HDIM + t * 8];
        *(float4*)orow = o0;
        *(float4*)(orow + 4) = o1;
    }
}

// ---------- mean pool: run-length accumulate (batch sorted) ----------
__global__ __launch_bounds__(256) void pool_kernel(
    const float* __restrict__ h, const int* __restrict__ batch,
    float* __restrict__ sums, float* __restrict__ cnt)
{
    int wid = blockIdx.x * 4 + (threadIdx.x >> 6);
    int n0 = wid * 64;
    if (n0 >= N_NODES) return;
    int lane = threadIdx.x & 63;
    int nend = min(n0 + 64, N_NODES);
    float acc = 0.f;
    int b_cur = batch[n0];
    int run = 0;
    for (int n = n0; n < nend; n++) {
        int b = batch[n];
        if (b != b_cur) {
            atomicAdd(&sums[b_cur * HDIM + lane], acc);
            if (lane == 0) atomicAdd(&cnt[b_cur], (float)run);
            acc = 0.f; run = 0; b_cur = b;
        }
        acc += h[(size_t)n * HDIM + lane];
        run++;
    }
    atomicAdd(&sums[b_cur * HDIM + lane], acc);
    if (lane == 0) atomicAdd(&cnt[b_cur], (float)run);
}

// ---------- head ----------
__global__ void head_kernel(
    const float* __restrict__ sums, const float* __restrict__ cnt,
    const float* __restrict__ Wl, const float* __restrict__ bl,
    float* __restrict__ out)
{
    int tid = threadIdx.x;
    if (tid >= NB * NC) return;
    int b = tid / NC, c = tid % NC;
    float cc = fmaxf(cnt[b], 1.0f);
    float acc = bl[c];
    #pragma unroll
    for (int f = 0; f < HDIM; f++)
        acc += (sums[b * HDIM + f] / cc) * Wl[c * HDIM + f];
    out[tid] = acc;
}

extern "C" void kernel_launch(void* const* d_in, const int* in_sizes, int n_in,
                              void* d_out, int out_size, void* d_ws, size_t ws_size,
                              hipStream_t stream)
{
    const float* x     = (const float*)d_in[0];
    const int*   ei    = (const int*)d_in[1];
    const int*   batch = (const int*)d_in[2];

    const float* W[3][4];
    const float* B[3][4];
    for (int l = 0; l < 3; l++)
        for (int j = 0; j < 4; j++) {
            W[l][j] = (const float*)d_in[3 + l * 8 + j * 2];
            B[l][j] = (const float*)d_in[3 + l * 8 + j * 2 + 1];
        }
    const float* Wl = (const float*)d_in[27];
    const float* bl = (const float*)d_in[28];
    float* out = (float*)d_out;

    const size_t NF = (size_t)N_NODES * HDIM;
    char* w = (char*)d_ws;
    float*          h       = (float*)w;          w += NF * 4;
    float*          q       = (float*)w;          w += NF * 4;
    unsigned short* k16     = (unsigned short*)w; w += NF * 2;
    unsigned short* v16     = (unsigned short*)w; w += NF * 2;
    float*          skip    = (float*)w;          w += NF * 4;
    int*            csr_src = (int*)w;            w += (size_t)N_EDGES * 4;
    int*            bedge   = (int*)w;            w += (size_t)N_EDGES * 4;
    int*            row_ptr = (int*)w;            w += (size_t)(N_NODES + 1) * 4;
    int*            bcnt    = (int*)w;            w += (size_t)NBUCK * 4;
    int*            bbase   = (int*)w;            w += (size_t)NBUCK * 4;
    int*            gcursor = (int*)w;            w += (size_t)NBUCK * 4;
    float*          sums    = (float*)w;          w += (size_t)NB * HDIM * 4;
    float*          cnt     = (float*)w;          w += (size_t)NB * 4;

    const int gemm_gx = (N_NODES + 63) / 64;
    const int node_gx = (N_NODES + 3) / 4;
    const int pool_gx = (N_NODES + 64 * 4 - 1) / (64 * 4);

    // ----- CSR build via LDS-staged counting sort (once; shared by all layers) -----
    hipMemsetAsync(bcnt, 0, (size_t)NBUCK * 4, stream);
    count_bucket<<<EW_GRID, 256, 0, stream>>>(ei, bcnt);
    scan_bucket<<<1, 256, 0, stream>>>(bcnt, bbase, gcursor);
    bucket_scatter<<<EW_GRID, 256, 0, stream>>>(ei, gcursor, bedge);
    csr_from_buckets<<<NBUCK, 256, 0, stream>>>(bedge, bbase, bcnt, row_ptr, csr_src);

    for (int l = 0; l < 3; l++) {
        if (l == 0) {
            qkvs_gemm_f<F_IN><<<gemm_gx, 256, 0, stream>>>(
                x, W[0][0], B[0][0], W[0][1], B[0][1],
                   W[0][2], B[0][2], W[0][3], B[0][3], q, k16, v16, skip);
        } else {
            qkvs_gemm_f<HDIM><<<gemm_gx, 256, 0, stream>>>(
                h, W[l][0], B[l][0], W[l][1], B[l][1],
                   W[l][2], B[l][2], W[l][3], B[l][3], q, k16, v16, skip);
        }
        attn_fused<<<node_gx, 256, 0, stream>>>(
            row_ptr, csr_src, q, k16, v16, skip, h, l < 2 ? 1 : 0);
    }

    hipMemsetAsync(sums, 0, (size_t)NB * HDIM * 4, stream);
    hipMemsetAsync(cnt,  0, (size_t)NB * 4, stream);
    pool_kernel<<<pool_gx, 256, 0, stream>>>(h, batch, sums, cnt);
    head_kernel<<<1, 640, 0, stream>>>(sums, cnt, Wl, bl, out);
}

// Round 13
// 490.378 us; speedup vs baseline: 1.8551x; 1.1130x over previous
//
#include <hip/hip_runtime.h>
#include <math.h>

#define N_NODES 100000
#define N_EDGES 1600000
#define NB 64
#define F_IN 128
#define HDIM 64
#define NC 10

#define BSHIFT 9
#define BUCKET_NODES (1 << BSHIFT)                          // 512
#define NBUCK ((N_NODES + BUCKET_NODES - 1) >> BSHIFT)      // 196
#define EW_CHUNK 4096
#define EW_GRID ((N_EDGES + EW_CHUNK - 1) / EW_CHUNK)       // 391

typedef __attribute__((ext_vector_type(8))) short bf16x8;
typedef __attribute__((ext_vector_type(4))) float f32x4;

// ---------- bf16 helpers ----------
__device__ __forceinline__ unsigned short f2bf(float f) {
    unsigned u = __float_as_uint(f);
    u += 0x7FFFu + ((u >> 16) & 1u);    // round to nearest even
    return (unsigned short)(u >> 16);
}
__device__ __forceinline__ float bf2f(unsigned short b) {
    return __uint_as_float((unsigned)b << 16);
}

// ---------- W split: W -> bf16 hi + bf16 lo (residual) ----------
__global__ __launch_bounds__(256) void wsplit(
    const float* __restrict__ W0, const float* __restrict__ W1,
    const float* __restrict__ W2, const float* __restrict__ W3,
    unsigned short* __restrict__ hi, unsigned short* __restrict__ lo, int n)
{
    int i = blockIdx.x * 256 + threadIdx.x;
    if (i >= 4 * n) return;
    const float* Ws[4] = {W0, W1, W2, W3};
    float w = Ws[i / n][i % n];
    unsigned short h = f2bf(w);
    hi[i] = h;
    lo[i] = f2bf(w - bf2f(h));
}

// ---------- fused q/k/v/skip GEMM via MFMA (bf16 3-term residual) ----------
// Wave = 32 rows (2 row-tiles of 16). No LDS, no barriers. A-frags held in regs.
// out = Xhi*Whi + Xlo*Whi + Xhi*Wlo  (fp32 MFMA accumulate).
template<int K>
__global__ __launch_bounds__(256) void qkvs_gemm_mfma(
    const float* __restrict__ xin,
    const unsigned short* __restrict__ whi,
    const unsigned short* __restrict__ wlo,
    const float* __restrict__ bq, const float* __restrict__ bk,
    const float* __restrict__ bv, const float* __restrict__ bs,
    float* __restrict__ q, unsigned short* __restrict__ k16,
    unsigned short* __restrict__ v16, float* __restrict__ sk)
{
    constexpr int NCH = K / 32;
    const int tid = threadIdx.x;
    const int wv  = tid >> 6;
    const int l   = tid & 63;
    const int lr  = l & 15;      // A-row / B-col / D-col within tile
    const int lg  = l >> 4;      // k-group (8 consecutive k) ; D-row group
    const int row0 = blockIdx.x * 128 + wv * 32;

    // ---- load X rows, split into bf16 hi/lo fragments ----
    bf16x8 Ahi[2][NCH], Alo[2][NCH];
    #pragma unroll
    for (int rt = 0; rt < 2; rt++) {
        int row = row0 + rt * 16 + lr;
        bool ok = row < N_NODES;
        const float* xr = xin + (size_t)(ok ? row : 0) * K + lg * 8;
        #pragma unroll
        for (int c = 0; c < NCH; c++) {
            float4 f0, f1;
            if (ok) {
                f0 = *(const float4*)(xr + c * 32);
                f1 = *(const float4*)(xr + c * 32 + 4);
            } else {
                f0 = make_float4(0.f, 0.f, 0.f, 0.f);
                f1 = f0;
            }
            float xv[8] = {f0.x, f0.y, f0.z, f0.w, f1.x, f1.y, f1.z, f1.w};
            #pragma unroll
            for (int j = 0; j < 8; j++) {
                unsigned short hb = f2bf(xv[j]);
                Ahi[rt][c][j] = (short)hb;
                Alo[rt][c][j] = (short)f2bf(xv[j] - bf2f(hb));
            }
        }
    }

    const float* Bm[4] = {bq, bk, bv, bs};

    for (int mat = 0; mat < 4; mat++) {
        for (int ct = 0; ct < 4; ct++) {
            const size_t wbase = (size_t)(mat * 64 + ct * 16 + lr) * K + lg * 8;
            f32x4 acc0 = {0.f, 0.f, 0.f, 0.f};
            f32x4 acc1 = {0.f, 0.f, 0.f, 0.f};
            #pragma unroll
            for (int c = 0; c < NCH; c++) {
                bf16x8 Bhi = *(const bf16x8*)&whi[wbase + c * 32];
                bf16x8 Blo = *(const bf16x8*)&wlo[wbase + c * 32];
                acc0 = __builtin_amdgcn_mfma_f32_16x16x32_bf16(Ahi[0][c], Bhi, acc0, 0, 0, 0);
                acc1 = __builtin_amdgcn_mfma_f32_16x16x32_bf16(Ahi[1][c], Bhi, acc1, 0, 0, 0);
                acc0 = __builtin_amdgcn_mfma_f32_16x16x32_bf16(Alo[0][c], Bhi, acc0, 0, 0, 0);
                acc1 = __builtin_amdgcn_mfma_f32_16x16x32_bf16(Alo[1][c], Bhi, acc1, 0, 0, 0);
                acc0 = __builtin_amdgcn_mfma_f32_16x16x32_bf16(Ahi[0][c], Blo, acc0, 0, 0, 0);
                acc1 = __builtin_amdgcn_mfma_f32_16x16x32_bf16(Ahi[1][c], Blo, acc1, 0, 0, 0);
            }
            float bias = Bm[mat][ct * 16 + lr];
            int colo = ct * 16 + lr;
            // D layout: row = rt*16 + lg*4 + i, col = lr (within tile)
            #pragma unroll
            for (int i = 0; i < 4; i++) {
                int row = row0 + lg * 4 + i;
                if (row < N_NODES) {
                    float val = acc0[i] + bias;
                    size_t off = (size_t)row * HDIM + colo;
                    if (mat == 0)      q[off]   = val;
                    else if (mat == 1) k16[off] = f2bf(val);
                    else if (mat == 2) v16[off] = f2bf(val);
                    else               sk[off]  = val;
                }
            }
            #pragma unroll
            for (int i = 0; i < 4; i++) {
                int row = row0 + 16 + lg * 4 + i;
                if (row < N_NODES) {
                    float val = acc1[i] + bias;
                    size_t off = (size_t)row * HDIM + colo;
                    if (mat == 0)      q[off]   = val;
                    else if (mat == 1) k16[off] = f2bf(val);
                    else if (mat == 2) v16[off] = f2bf(val);
                    else               sk[off]  = val;
                }
            }
        }
    }
}

// ---------- CSR build, stage 1: per-bucket edge counts (LDS hist only) ----------
__global__ __launch_bounds__(256) void count_bucket(
    const int* __restrict__ ei, int* __restrict__ bcnt)
{
    __shared__ int hist[NBUCK];
    for (int i = threadIdx.x; i < NBUCK; i += 256) hist[i] = 0;
    __syncthreads();
    int e0 = blockIdx.x * EW_CHUNK;
    #pragma unroll
    for (int i = 0; i < EW_CHUNK / 256; i++) {
        int e = e0 + i * 256 + threadIdx.x;
        if (e < N_EDGES) atomicAdd(&hist[ei[N_EDGES + e] >> BSHIFT], 1);
    }
    __syncthreads();
    for (int i = threadIdx.x; i < NBUCK; i += 256)
        if (hist[i]) atomicAdd(&bcnt[i], hist[i]);
}

// ---------- CSR build, stage 2: bucket base scan (196 values, one block) ----------
__global__ __launch_bounds__(256) void scan_bucket(
    const int* __restrict__ bcnt, int* __restrict__ bbase, int* __restrict__ gcursor)
{
    __shared__ int sh[256];
    int t = threadIdx.x;
    int v = (t < NBUCK) ? bcnt[t] : 0;
    sh[t] = v;
    __syncthreads();
    for (int off = 1; off < 256; off <<= 1) {
        int u = (t >= off) ? sh[t - off] : 0;
        __syncthreads();
        sh[t] += u;
        __syncthreads();
    }
    if (t < NBUCK) { bbase[t] = sh[t] - v; gcursor[t] = sh[t] - v; }
}

// ---------- CSR build, stage 3: scatter packed edges into bucket order ----------
// packed entry: (dst_local << 17) | src
__global__ __launch_bounds__(256) void bucket_scatter(
    const int* __restrict__ ei, int* __restrict__ gcursor, int* __restrict__ bedge)
{
    __shared__ int hist[NBUCK];
    __shared__ int base[NBUCK];
    for (int i = threadIdx.x; i < NBUCK; i += 256) hist[i] = 0;
    __syncthreads();
    int e0 = blockIdx.x * EW_CHUNK;
    #pragma unroll
    for (int i = 0; i < EW_CHUNK / 256; i++) {
        int e = e0 + i * 256 + threadIdx.x;
        if (e < N_EDGES) atomicAdd(&hist[ei[N_EDGES + e] >> BSHIFT], 1);
    }
    __syncthreads();
    for (int i = threadIdx.x; i < NBUCK; i += 256)
        base[i] = hist[i] ? atomicAdd(&gcursor[i], hist[i]) : 0;
    __syncthreads();
    for (int i = threadIdx.x; i < NBUCK; i += 256) hist[i] = 0;
    __syncthreads();
    #pragma unroll
    for (int i = 0; i < EW_CHUNK / 256; i++) {
        int e = e0 + i * 256 + threadIdx.x;
        if (e < N_EDGES) {
            int src = ei[e];
            int dst = ei[N_EDGES + e];
            int b = dst >> BSHIFT;
            int pos = base[b] + atomicAdd(&hist[b], 1);
            bedge[pos] = ((dst & (BUCKET_NODES - 1)) << 17) | src;
        }
    }
}

// ---------- CSR build, stage 4: one WG per bucket ----------
__global__ __launch_bounds__(256) void csr_from_buckets(
    const int* __restrict__ bedge, const int* __restrict__ bbase,
    const int* __restrict__ bcnt, int* __restrict__ row_ptr,
    int* __restrict__ csr_src)
{
    __shared__ int cur[BUCKET_NODES];   // 512
    __shared__ int psum[256];
    const int b = blockIdx.x;
    const int dst0 = b << BSHIFT;
    const int t = threadIdx.x;

    for (int i = t; i < BUCKET_NODES; i += 256) cur[i] = 0;
    __syncthreads();

    const int beg = bbase[b], cnt = bcnt[b];
    for (int i = t; i < cnt; i += 256)
        atomicAdd(&cur[bedge[beg + i] >> 17], 1);
    __syncthreads();

    int a0 = cur[2 * t], a1 = cur[2 * t + 1];
    int pair = a0 + a1;
    psum[t] = pair;
    __syncthreads();
    for (int off = 1; off < 256; off <<= 1) {
        int u = (t >= off) ? psum[t - off] : 0;
        __syncthreads();
        psum[t] += u;
        __syncthreads();
    }
    int ex = psum[t] - pair;            // exclusive prefix of this pair

    int d0 = dst0 + 2 * t, d1 = d0 + 1;
    int g0 = beg + ex, g1 = beg + ex + a0;
    if (d0 < N_NODES) row_ptr[d0] = g0;
    if (d1 < N_NODES) row_ptr[d1] = g1;
    if (b == gridDim.x - 1 && t == 255) row_ptr[N_NODES] = beg + psum[255];
    cur[2 * t] = g0;
    cur[2 * t + 1] = g1;
    __syncthreads();

    for (int i = t; i < cnt; i += 256) {
        int ed = bedge[beg + i];
        int pos = atomicAdd(&cur[ed >> 17], 1);
        csr_src[pos] = ed & 0x1FFFF;
    }
}

// ---------- fused attention: wave per dst, 8 edges/iter, bf16 k/v gathers ----------
__global__ __launch_bounds__(256) void attn_fused(
    const int* __restrict__ row_ptr, const int* __restrict__ csr_src,
    const float* __restrict__ q, const unsigned short* __restrict__ k16,
    const unsigned short* __restrict__ v16, const float* __restrict__ skip,
    float* __restrict__ hout, int do_relu)
{
    int n = blockIdx.x * 4 + (threadIdx.x >> 6);
    if (n >= N_NODES) return;
    int lane = threadIdx.x & 63;
    int g = lane >> 3;
    int t = lane & 7;
    int beg = row_ptr[n], end = row_ptr[n + 1];

    const float* qrow = &q[(size_t)n * HDIM + t * 8];
    float4 qa = *(const float4*)qrow;
    float4 qb = *(const float4*)(qrow + 4);
    float m = -1e30f, s = 0.f;
    float4 aca = make_float4(0.f, 0.f, 0.f, 0.f);
    float4 acb = make_float4(0.f, 0.f, 0.f, 0.f);

    for (int i = beg; i < end; i += 8) {
        int e = i + g;
        bool valid = (e < end);
        int src = csr_src[valid ? e : beg];
        uint4 ku = *(const uint4*)&k16[(size_t)src * HDIM + t * 8];
        uint4 vu = *(const uint4*)&v16[(size_t)src * HDIM + t * 8];
        float p = qa.x * __uint_as_float(ku.x << 16)
                + qa.y * __uint_as_float(ku.x & 0xFFFF0000u)
                + qa.z * __uint_as_float(ku.y << 16)
                + qa.w * __uint_as_float(ku.y & 0xFFFF0000u)
                + qb.x * __uint_as_float(ku.z << 16)
                + qb.y * __uint_as_float(ku.z & 0xFFFF0000u)
                + qb.z * __uint_as_float(ku.w << 16)
                + qb.w * __uint_as_float(ku.w & 0xFFFF0000u);
        p += __shfl_xor(p, 1, 64);
        p += __shfl_xor(p, 2, 64);
        p += __shfl_xor(p, 4, 64);
        float a = valid ? p * 0.125f : -INFINITY;
        float mn = fmaxf(m, a);
        float sc = __expf(m - mn);
        float ew = __expf(a - mn);
        s = s * sc + ew;
        aca.x = aca.x * sc + ew * __uint_as_float(vu.x << 16);
        aca.y = aca.y * sc + ew * __uint_as_float(vu.x & 0xFFFF0000u);
        aca.z = aca.z * sc + ew * __uint_as_float(vu.y << 16);
        aca.w = aca.w * sc + ew * __uint_as_float(vu.y & 0xFFFF0000u);
        acb.x = acb.x * sc + ew * __uint_as_float(vu.z << 16);
        acb.y = acb.y * sc + ew * __uint_as_float(vu.z & 0xFFFF0000u);
        acb.z = acb.z * sc + ew * __uint_as_float(vu.w << 16);
        acb.w = acb.w * sc + ew * __uint_as_float(vu.w & 0xFFFF0000u);
        m = mn;
    }

    #pragma unroll
    for (int off = 8; off <= 32; off <<= 1) {
        float m2 = __shfl_xor(m, off, 64);
        float s2 = __shfl_xor(s, off, 64);
        float x0 = __shfl_xor(aca.x, off, 64);
        float x1 = __shfl_xor(aca.y, off, 64);
        float x2 = __shfl_xor(aca.z, off, 64);
        float x3 = __shfl_xor(aca.w, off, 64);
        float x4 = __shfl_xor(acb.x, off, 64);
        float x5 = __shfl_xor(acb.y, off, 64);
        float x6 = __shfl_xor(acb.z, off, 64);
        float x7 = __shfl_xor(acb.w, off, 64);
        float mn = fmaxf(m, m2);
        float c1 = __expf(m - mn);
        float c2 = __expf(m2 - mn);
        s = s * c1 + s2 * c2;
        aca.x = aca.x * c1 + x0 * c2;
        aca.y = aca.y * c1 + x1 * c2;
        aca.z = aca.z * c1 + x2 * c2;
        aca.w = aca.w * c1 + x3 * c2;
        acb.x = acb.x * c1 + x4 * c2;
        acb.y = acb.y * c1 + x5 * c2;
        acb.z = acb.z * c1 + x6 * c2;
        acb.w = acb.w * c1 + x7 * c2;
        m = mn;
    }

    if (g == 0) {
        float inv = (s > 0.f) ? (1.f / s) : 0.f;
        const float* skrow = &skip[(size_t)n * HDIM + t * 8];
        float4 s0 = *(const float4*)skrow;
        float4 s1 = *(const float4*)(skrow + 4);
        float4 o0, o1;
        o0.x = aca.x * inv + s0.x;
        o0.y = aca.y * inv + s0.y;
        o0.z = aca.z * inv + s0.z;
        o0.w = aca.w * inv + s0.w;
        o1.x = acb.x * inv + s1.x;
        o1.y = acb.y * inv + s1.y;
        o1.z = acb.z * inv + s1.z;
        o1.w = acb.w * inv + s1.w;
        if (do_relu) {
            o0.x = fmaxf(o0.x, 0.f); o0.y = fmaxf(o0.y, 0.f);
            o0.z = fmaxf(o0.z, 0.f); o0.w = fmaxf(o0.w, 0.f);
            o1.x = fmaxf(o1.x, 0.f); o1.y = fmaxf(o1.y, 0.f);
            o1.z = fmaxf(o1.z, 0.f); o1.w = fmaxf(o1.w, 0.f);
        }
        float* orow = &hout[(size_t)n * HDIM + t * 8];
        *(float4*)orow = o0;
        *(float4*)(orow + 4) = o1;
    }
}

// ---------- mean pool: run-length accumulate (batch sorted) ----------
__global__ __launch_bounds__(256) void pool_kernel(
    const float* __restrict__ h, const int* __restrict__ batch,
    float* __restrict__ sums, float* __restrict__ cnt)
{
    int wid = blockIdx.x * 4 + (threadIdx.x >> 6);
    int n0 = wid * 64;
    if (n0 >= N_NODES) return;
    int lane = threadIdx.x & 63;
    int nend = min(n0 + 64, N_NODES);
    float acc = 0.f;
    int b_cur = batch[n0];
    int run = 0;
    for (int n = n0; n < nend; n++) {
        int b = batch[n];
        if (b != b_cur) {
            atomicAdd(&sums[b_cur * HDIM + lane], acc);
            if (lane == 0) atomicAdd(&cnt[b_cur], (float)run);
            acc = 0.f; run = 0; b_cur = b;
        }
        acc += h[(size_t)n * HDIM + lane];
        run++;
    }
    atomicAdd(&sums[b_cur * HDIM + lane], acc);
    if (lane == 0) atomicAdd(&cnt[b_cur], (float)run);
}

// ---------- head ----------
__global__ void head_kernel(
    const float* __restrict__ sums, const float* __restrict__ cnt,
    const float* __restrict__ Wl, const float* __restrict__ bl,
    float* __restrict__ out)
{
    int tid = threadIdx.x;
    if (tid >= NB * NC) return;
    int b = tid / NC, c = tid % NC;
    float cc = fmaxf(cnt[b], 1.0f);
    float acc = bl[c];
    #pragma unroll
    for (int f = 0; f < HDIM; f++)
        acc += (sums[b * HDIM + f] / cc) * Wl[c * HDIM + f];
    out[tid] = acc;
}

extern "C" void kernel_launch(void* const* d_in, const int* in_sizes, int n_in,
                              void* d_out, int out_size, void* d_ws, size_t ws_size,
                              hipStream_t stream)
{
    const float* x     = (const float*)d_in[0];
    const int*   ei    = (const int*)d_in[1];
    const int*   batch = (const int*)d_in[2];

    const float* W[3][4];
    const float* B[3][4];
    for (int l = 0; l < 3; l++)
        for (int j = 0; j < 4; j++) {
            W[l][j] = (const float*)d_in[3 + l * 8 + j * 2];
            B[l][j] = (const float*)d_in[3 + l * 8 + j * 2 + 1];
        }
    const float* Wl = (const float*)d_in[27];
    const float* bl = (const float*)d_in[28];
    float* out = (float*)d_out;

    const size_t NF = (size_t)N_NODES * HDIM;
    char* w = (char*)d_ws;
    float*          h       = (float*)w;          w += NF * 4;
    float*          q       = (float*)w;          w += NF * 4;
    unsigned short* k16     = (unsigned short*)w; w += NF * 2;
    unsigned short* v16     = (unsigned short*)w; w += NF * 2;
    float*          skip    = (float*)w;          w += NF * 4;
    int*            csr_src = (int*)w;            w += (size_t)N_EDGES * 4;
    int*            bedge   = (int*)w;            w += (size_t)N_EDGES * 4;
    int*            row_ptr = (int*)w;            w += (size_t)(N_NODES + 1) * 4;
    int*            bcnt    = (int*)w;            w += (size_t)NBUCK * 4;
    int*            bbase   = (int*)w;            w += (size_t)NBUCK * 4;
    int*            gcursor = (int*)w;            w += (size_t)NBUCK * 4;
    float*          sums    = (float*)w;          w += (size_t)NB * HDIM * 4;
    float*          cnt     = (float*)w;          w += (size_t)NB * 4;
    unsigned short* whi[3];
    unsigned short* wlo[3];
    const int wsz[3] = {64 * F_IN, 64 * HDIM, 64 * HDIM};   // per-mat elems
    for (int l = 0; l < 3; l++) {
        whi[l] = (unsigned short*)w; w += (size_t)4 * wsz[l] * 2;
        wlo[l] = (unsigned short*)w; w += (size_t)4 * wsz[l] * 2;
    }

    const int gemm_gx = (N_NODES + 127) / 128;
    const int node_gx = (N_NODES + 3) / 4;
    const int pool_gx = (N_NODES + 64 * 4 - 1) / (64 * 4);

    // ----- W split to bf16 hi/lo (once) -----
    for (int l = 0; l < 3; l++) {
        int n = wsz[l];
        wsplit<<<(4 * n + 255) / 256, 256, 0, stream>>>(
            W[l][0], W[l][1], W[l][2], W[l][3], whi[l], wlo[l], n);
    }

    // ----- CSR build via LDS-staged counting sort (once; shared by all layers) -----
    hipMemsetAsync(bcnt, 0, (size_t)NBUCK * 4, stream);
    count_bucket<<<EW_GRID, 256, 0, stream>>>(ei, bcnt);
    scan_bucket<<<1, 256, 0, stream>>>(bcnt, bbase, gcursor);
    bucket_scatter<<<EW_GRID, 256, 0, stream>>>(ei, gcursor, bedge);
    csr_from_buckets<<<NBUCK, 256, 0, stream>>>(bedge, bbase, bcnt, row_ptr, csr_src);

    for (int l = 0; l < 3; l++) {
        if (l == 0) {
            qkvs_gemm_mfma<F_IN><<<gemm_gx, 256, 0, stream>>>(
                x, whi[0], wlo[0], B[0][0], B[0][1], B[0][2], B[0][3],
                q, k16, v16, skip);
        } else {
            qkvs_gemm_mfma<HDIM><<<gemm_gx, 256, 0, stream>>>(
                h, whi[l], wlo[l], B[l][0], B[l][1], B[l][2], B[l][3],
                q, k16, v16, skip);
        }
        attn_fused<<<node_gx, 256, 0, stream>>>(
            row_ptr, csr_src, q, k16, v16, skip, h, l < 2 ? 1 : 0);
    }

    hipMemsetAsync(sums, 0, (size_t)NB * HDIM * 4, stream);
    hipMemsetAsync(cnt,  0, (size_t)NB * 4, stream);
    pool_kernel<<<pool_gx, 256, 0, stream>>>(h, batch, sums, cnt);
    head_kernel<<<1, 640, 0, stream>>>(sums, cnt, Wl, bl, out);
}